// Round 1
// baseline (343.832 us; speedup 1.0000x reference)
//
#include <hip/hip_runtime.h>
#include <hip/hip_bf16.h>

#define B_SZ 4096
#define F_CAT 26
#define NUM_N 13
#define ED 64
#define D_DIM 1728   // 27*64
#define E_EXP 8
#define T_TASK 2
#define BOT0 512
#define BOT1 256
#define TOW0 128
#define TOW1 64

typedef __bf16 bf16x8 __attribute__((ext_vector_type(8)));
typedef float f32x4 __attribute__((ext_vector_type(4)));

__device__ __forceinline__ void gload_lds16(const void* g, void* l) {
  __builtin_amdgcn_global_load_lds(
      (const __attribute__((address_space(1))) void*)g,
      (__attribute__((address_space(3))) void*)l, 16, 0, 0);
}

// ---------------- transpose + fp32->bf16 convert: in (R,C) f32 -> out (C,R) bf16, batched over z
__global__ __launch_bounds__(256) void transpose_to_bf16(
    const float* __restrict__ in, __hip_bfloat16* __restrict__ out, int R, int C)
{
  __shared__ float tile[32][33];
  const float* inp = in + (size_t)blockIdx.z * R * C;
  __hip_bfloat16* outp = out + (size_t)blockIdx.z * R * C;
  int c0 = blockIdx.x * 32, r0 = blockIdx.y * 32;
  int tx = threadIdx.x & 31, ty = threadIdx.x >> 5; // 32 x 8
#pragma unroll
  for (int i = 0; i < 32; i += 8)
    tile[ty + i][tx] = inp[(size_t)(r0 + ty + i) * C + c0 + tx];
  __syncthreads();
#pragma unroll
  for (int i = 0; i < 32; i += 8)
    outp[(size_t)(c0 + ty + i) * R + r0 + tx] = __float2bfloat16(tile[tx][ty + i]);
}

// ---------------- embedding gather + numeric linear + gate softmax (one block per batch row)
__global__ __launch_bounds__(256) void embed_gate(
    const int* __restrict__ cat, const float* __restrict__ numx,
    const int* __restrict__ offsets, const float* __restrict__ W_emb,
    const float* __restrict__ Wn, const float* __restrict__ bnum,
    const float* __restrict__ Wg, const float* __restrict__ bg,
    __hip_bfloat16* __restrict__ emb, float* __restrict__ gate)
{
  int b = blockIdx.x;
  int tid = threadIdx.x;
  __shared__ float es[D_DIM];
  __shared__ float sg[T_TASK * E_EXP];
  const int* crow = cat + (size_t)b * F_CAT;
  for (int i = tid; i < F_CAT * ED; i += 256) {
    int f = i >> 6, d = i & 63;
    size_t row = (size_t)(crow[f] + offsets[f]);
    float v = W_emb[row * ED + d];
    es[i] = v;
    emb[(size_t)b * D_DIM + i] = __float2bfloat16(v);
  }
  if (tid < ED) {
    float a = bnum[tid];
#pragma unroll
    for (int n = 0; n < NUM_N; ++n)
      a = fmaf(numx[(size_t)b * NUM_N + n], Wn[n * ED + tid], a);
    es[F_CAT * ED + tid] = a;
    emb[(size_t)b * D_DIM + F_CAT * ED + tid] = __float2bfloat16(a);
  }
  __syncthreads();
  // gate logits: 16 (t,e) pairs x 16 lanes each
  int g = tid >> 4, l16 = tid & 15;
  int t = g >> 3, e = g & 7;
  float p = 0.f;
  for (int d = l16; d < D_DIM; d += 16)
    p = fmaf(es[d], Wg[((size_t)t * D_DIM + d) * E_EXP + e], p);
#pragma unroll
  for (int o = 8; o; o >>= 1) p += __shfl_down(p, o, 16);
  if (l16 == 0) sg[g] = p + bg[t * E_EXP + e];
  __syncthreads();
  if (tid < T_TASK) {
    float m = sg[tid * 8];
#pragma unroll
    for (int k = 1; k < 8; ++k) m = fmaxf(m, sg[tid * 8 + k]);
    float s = 0.f;
    float ex[8];
#pragma unroll
    for (int k = 0; k < 8; ++k) { ex[k] = expf(sg[tid * 8 + k] - m); s += ex[k]; }
    float inv = 1.f / s;
#pragma unroll
    for (int k = 0; k < 8; ++k)
      gate[((size_t)tid * B_SZ + b) * E_EXP + k] = ex[k] * inv;
  }
}

// ---------------- bf16 MFMA GEMM: C[e] = relu(A[e] (MxK) * BT[e]^T (NxK) + bias[e]) -> bf16
// m97 structure: 128x128 tile, BK=32, 4 waves of 64x64, global_load_lds width 16.
template <int BM, int BN, int BK>
__global__ __launch_bounds__(256) void gemm_bt_bias_relu(
    const __hip_bfloat16* __restrict__ A, size_t strideAe,
    const __hip_bfloat16* __restrict__ BT,
    const float* __restrict__ bias,
    __hip_bfloat16* __restrict__ C,
    int M, int N, int K)
{
  int e = blockIdx.z;
  const __hip_bfloat16* Ap = A + strideAe * (size_t)e;
  const __hip_bfloat16* Bp = BT + (size_t)e * N * K;
  const float* bp = bias + (size_t)e * N;
  __hip_bfloat16* Cp = C + (size_t)e * M * N;
  int bm0 = blockIdx.x * BM, bn0 = blockIdx.y * BN;

  __shared__ __align__(16) __hip_bfloat16 As[BM * BK]; // 8 KB
  __shared__ __align__(16) __hip_bfloat16 Bs[BN * BK]; // 8 KB

  int tid = threadIdx.x;
  int wid = tid >> 6, lane = tid & 63;
  int l15 = lane & 15, lh = lane >> 4;
  int wm = (wid >> 1) * 64, wn = (wid & 1) * 64;

  f32x4 acc[4][4] = {};

  int r0 = tid >> 2;        // staging row (0..63)
  int c0e = (tid & 3) * 8;  // staging col (elements)
  char* AsB = (char*)As;
  char* BsB = (char*)Bs;
  int ldsOff = wid * 1024;  // wave-uniform LDS base; HW adds lane*16

  for (int kt = 0; kt < K; kt += BK) {
    __syncthreads();
#pragma unroll
    for (int j = 0; j < 2; ++j) {
      gload_lds16(Ap + (size_t)(bm0 + r0 + j * 64) * K + kt + c0e, AsB + ldsOff + j * 4096);
      gload_lds16(Bp + (size_t)(bn0 + r0 + j * 64) * K + kt + c0e, BsB + ldsOff + j * 4096);
    }
    __syncthreads();
    bf16x8 af[4], bf[4];
#pragma unroll
    for (int mi = 0; mi < 4; ++mi)
      af[mi] = *reinterpret_cast<const bf16x8*>(&As[(wm + mi * 16 + l15) * BK + lh * 8]);
#pragma unroll
    for (int nj = 0; nj < 4; ++nj)
      bf[nj] = *reinterpret_cast<const bf16x8*>(&Bs[(wn + nj * 16 + l15) * BK + lh * 8]);
#pragma unroll
    for (int mi = 0; mi < 4; ++mi)
#pragma unroll
      for (int nj = 0; nj < 4; ++nj)
        acc[mi][nj] = __builtin_amdgcn_mfma_f32_16x16x32_bf16(af[mi], bf[nj], acc[mi][nj], 0, 0, 0);
  }

#pragma unroll
  for (int nj = 0; nj < 4; ++nj) {
    int col = bn0 + wn + nj * 16 + l15;
    float bv = bp[col];
#pragma unroll
    for (int mi = 0; mi < 4; ++mi) {
      int rb = bm0 + wm + mi * 16 + lh * 4;
#pragma unroll
      for (int r = 0; r < 4; ++r) {
        float v = acc[mi][nj][r] + bv;
        v = fmaxf(v, 0.f);
        Cp[(size_t)(rb + r) * N + col] = __float2bfloat16(v);
      }
    }
  }
}

// ---------------- gate-combine + tower MLPs + sigmoid (16 batch rows per block)
#define TB 16
__global__ __launch_bounds__(256) void combine_tower(
    const float* __restrict__ gate, const __hip_bfloat16* __restrict__ fea,
    const float* __restrict__ Wt1, const float* __restrict__ bt1,
    const float* __restrict__ Wt2, const float* __restrict__ bt2,
    const float* __restrict__ Wt3, const float* __restrict__ bt3,
    float* __restrict__ out)
{
  int t = blockIdx.y;
  int b0 = blockIdx.x * TB;
  int tid = threadIdx.x;
  __shared__ float gs[TB][E_EXP];
  __shared__ float tf[TB][BOT1];
  __shared__ float h1[TB][TOW0];
  __shared__ float h2[TB][TOW1];
  if (tid < TB * E_EXP) {
    int bl = tid >> 3, e = tid & 7;
    gs[bl][e] = gate[((size_t)t * B_SZ + b0 + bl) * E_EXP + e];
  }
  __syncthreads();
  // task_fea = sum_e gate * fea
  for (int i = tid; i < TB * BOT1; i += 256) {
    int bl = i >> 8, o = i & 255;
    float s = 0.f;
#pragma unroll
    for (int e = 0; e < E_EXP; ++e)
      s = fmaf(gs[bl][e], __bfloat162float(fea[((size_t)e * B_SZ + b0 + bl) * BOT1 + o]), s);
    tf[bl][o] = s;
  }
  __syncthreads();
  // tower layer 1: 256 -> 128
  {
    int h = tid & 127, half = tid >> 7;
    float a[8] = {0, 0, 0, 0, 0, 0, 0, 0};
    for (int d = 0; d < BOT1; ++d) {
      float w = Wt1[((size_t)t * BOT1 + d) * TOW0 + h];
#pragma unroll
      for (int q = 0; q < 8; ++q) a[q] = fmaf(w, tf[half * 8 + q][d], a[q]);
    }
    float bv = bt1[t * TOW0 + h];
#pragma unroll
    for (int q = 0; q < 8; ++q) h1[half * 8 + q][h] = fmaxf(a[q] + bv, 0.f);
  }
  __syncthreads();
  // tower layer 2: 128 -> 64
  {
    int h = tid & 63, qt = tid >> 6;
    float a[4] = {0, 0, 0, 0};
    for (int d = 0; d < TOW0; ++d) {
      float w = Wt2[((size_t)t * TOW0 + d) * TOW1 + h];
#pragma unroll
      for (int q = 0; q < 4; ++q) a[q] = fmaf(w, h1[qt * 4 + q][d], a[q]);
    }
    float bv = bt2[t * TOW1 + h];
#pragma unroll
    for (int q = 0; q < 4; ++q) h2[qt * 4 + q][h] = fmaxf(a[q] + bv, 0.f);
  }
  __syncthreads();
  // tower layer 3: 64 -> 1 + sigmoid
  {
    int l16 = tid & 15, bl = tid >> 4;
    float p = 0.f;
#pragma unroll
    for (int d = l16; d < TOW1; d += 16) p = fmaf(h2[bl][d], Wt3[t * TOW1 + d], p);
#pragma unroll
    for (int o = 8; o; o >>= 1) p += __shfl_down(p, o, 16);
    if (l16 == 0) {
      float lg = p + bt3[t];
      out[(size_t)t * B_SZ + b0 + bl] = 1.f / (1.f + expf(-lg));
    }
  }
}

extern "C" void kernel_launch(void* const* d_in, const int* in_sizes, int n_in,
                              void* d_out, int out_size, void* d_ws, size_t ws_size,
                              hipStream_t stream) {
  const int* cat = (const int*)d_in[0];
  const float* numx = (const float*)d_in[1];
  const int* offsets = (const int*)d_in[2];
  const float* W_emb = (const float*)d_in[3];
  const float* Wn = (const float*)d_in[4];
  const float* bnv = (const float*)d_in[5];
  const float* We1 = (const float*)d_in[6];
  const float* be1 = (const float*)d_in[7];
  const float* We2 = (const float*)d_in[8];
  const float* be2 = (const float*)d_in[9];
  const float* Wg = (const float*)d_in[10];
  const float* bg = (const float*)d_in[11];
  const float* Wt1 = (const float*)d_in[12];
  const float* bt1 = (const float*)d_in[13];
  const float* Wt2 = (const float*)d_in[14];
  const float* bt2 = (const float*)d_in[15];
  const float* Wt3 = (const float*)d_in[16];
  const float* bt3 = (const float*)d_in[17];
  float* out = (float*)d_out;

  char* ws = (char*)d_ws;
  size_t off = 0;
  auto alloc = [&](size_t bytes) {
    char* p = ws + off;
    off += (bytes + 255) & ~(size_t)255;
    return p;
  };
  __hip_bfloat16* emb  = (__hip_bfloat16*)alloc((size_t)B_SZ * D_DIM * 2);
  __hip_bfloat16* We1T = (__hip_bfloat16*)alloc((size_t)E_EXP * BOT0 * D_DIM * 2);
  __hip_bfloat16* We2T = (__hip_bfloat16*)alloc((size_t)E_EXP * BOT1 * BOT0 * 2);
  __hip_bfloat16* H    = (__hip_bfloat16*)alloc((size_t)E_EXP * B_SZ * BOT0 * 2);
  __hip_bfloat16* fea  = (__hip_bfloat16*)alloc((size_t)E_EXP * B_SZ * BOT1 * 2);
  float* gate = (float*)alloc((size_t)T_TASK * B_SZ * E_EXP * 4);

  // 1. weight transpose/convert: We1 (e,1728,512)->(e,512,1728) bf16; We2 (e,512,256)->(e,256,512) bf16
  transpose_to_bf16<<<dim3(BOT0 / 32, D_DIM / 32, E_EXP), 256, 0, stream>>>(We1, We1T, D_DIM, BOT0);
  transpose_to_bf16<<<dim3(BOT1 / 32, BOT0 / 32, E_EXP), 256, 0, stream>>>(We2, We2T, BOT0, BOT1);

  // 2. embedding + numeric + gate softmax
  embed_gate<<<dim3(B_SZ), 256, 0, stream>>>(cat, numx, offsets, W_emb, Wn, bnv, Wg, bg, emb, gate);

  // 3. expert layer 1: (4096x1728)x(1728x512) x8 -> H
  gemm_bt_bias_relu<128, 128, 32><<<dim3(B_SZ / 128, BOT0 / 128, E_EXP), 256, 0, stream>>>(
      emb, (size_t)0, We1T, be1, H, B_SZ, BOT0, D_DIM);

  // 4. expert layer 2: (4096x512)x(512x256) x8 -> fea
  gemm_bt_bias_relu<128, 128, 32><<<dim3(B_SZ / 128, BOT1 / 128, E_EXP), 256, 0, stream>>>(
      H, (size_t)B_SZ * BOT0, We2T, be2, fea, B_SZ, BOT1, BOT0);

  // 5. gated combine + towers + sigmoid
  combine_tower<<<dim3(B_SZ / TB, T_TASK), 256, 0, stream>>>(
      gate, fea, Wt1, bt1, Wt2, bt2, Wt3, bt3, out);
}

// Round 2
// 173.964 us; speedup vs baseline: 1.9765x; 1.9765x over previous
//
#include <hip/hip_runtime.h>
#include <hip/hip_bf16.h>

#define B_SZ 4096
#define F_CAT 26
#define NUM_N 13
#define ED 64
#define D_DIM 1728   // 27*64
#define E_EXP 8
#define T_TASK 2
#define BOT0 512
#define BOT1 256
#define TOW0 128
#define TOW1 64

typedef __bf16 bf16x8 __attribute__((ext_vector_type(8)));
typedef float f32x4 __attribute__((ext_vector_type(4)));

__device__ __forceinline__ void gload_lds16(const void* g, void* l) {
  __builtin_amdgcn_global_load_lds(
      (const __attribute__((address_space(1))) void*)g,
      (__attribute__((address_space(3))) void*)l, 16, 0, 0);
}

// ---------------- transpose + fp32->bf16 convert: in (R,C) f32 -> out (C,R) bf16, batched over z
__global__ __launch_bounds__(256) void transpose_to_bf16(
    const float* __restrict__ in, __hip_bfloat16* __restrict__ out, int R, int C)
{
  __shared__ float tile[32][33];
  const float* inp = in + (size_t)blockIdx.z * R * C;
  __hip_bfloat16* outp = out + (size_t)blockIdx.z * R * C;
  int c0 = blockIdx.x * 32, r0 = blockIdx.y * 32;
  int tx = threadIdx.x & 31, ty = threadIdx.x >> 5; // 32 x 8
#pragma unroll
  for (int i = 0; i < 32; i += 8)
    tile[ty + i][tx] = inp[(size_t)(r0 + ty + i) * C + c0 + tx];
  __syncthreads();
#pragma unroll
  for (int i = 0; i < 32; i += 8)
    outp[(size_t)(c0 + ty + i) * R + r0 + tx] = __float2bfloat16(tile[tx][ty + i]);
}

// ---------------- Wg (T,D,E) f32 -> WgT (T*E, D) bf16
__global__ __launch_bounds__(256) void wg_transpose(
    const float* __restrict__ Wg, __hip_bfloat16* __restrict__ WgT)
{
  int i = blockIdx.x * 256 + threadIdx.x; // over 16*1728
  int n = i / D_DIM, d = i - n * D_DIM;
  int t = n >> 3, e = n & 7;
  WgT[i] = __float2bfloat16(Wg[((size_t)t * D_DIM + d) * E_EXP + e]);
}

// ---------------- embedding gather + numeric linear -> emb bf16 (4 batch rows / block)
__global__ __launch_bounds__(256) void embed_convert(
    const int* __restrict__ cat, const float* __restrict__ numx,
    const int* __restrict__ offsets, const float* __restrict__ W_emb,
    const float* __restrict__ Wn, const float* __restrict__ bnum,
    __hip_bfloat16* __restrict__ emb)
{
  const int UNITS = 27 * 16; // float4 units per row
  int b0 = blockIdx.x * 4;
  for (int idx = threadIdx.x; idx < 4 * UNITS; idx += 256) {
    int r = idx / UNITS, u = idx - r * UNITS;
    int f = u >> 4, d4 = (u & 15) * 4;
    int b = b0 + r;
    float4 v;
    if (f < F_CAT) {
      int row = cat[(size_t)b * F_CAT + f] + offsets[f];
      v = *reinterpret_cast<const float4*>(&W_emb[(size_t)row * ED + d4]);
    } else {
      float a0 = bnum[d4], a1 = bnum[d4 + 1], a2 = bnum[d4 + 2], a3 = bnum[d4 + 3];
#pragma unroll
      for (int n = 0; n < NUM_N; ++n) {
        float x = numx[(size_t)b * NUM_N + n];
        const float* wr = &Wn[n * ED + d4];
        a0 = fmaf(x, wr[0], a0);
        a1 = fmaf(x, wr[1], a1);
        a2 = fmaf(x, wr[2], a2);
        a3 = fmaf(x, wr[3], a3);
      }
      v = make_float4(a0, a1, a2, a3);
    }
    union { __hip_bfloat16 h[4]; uint2 u2; } pk;
    pk.h[0] = __float2bfloat16(v.x);
    pk.h[1] = __float2bfloat16(v.y);
    pk.h[2] = __float2bfloat16(v.z);
    pk.h[3] = __float2bfloat16(v.w);
    *reinterpret_cast<uint2*>(&emb[(size_t)b * D_DIM + f * ED + d4]) = pk.u2;
  }
}

// ---------------- gate GEMM (M=4096, N=16, K=1728) via MFMA + fused per-task softmax
__global__ __launch_bounds__(256) void gate_mfma(
    const __hip_bfloat16* __restrict__ emb, const __hip_bfloat16* __restrict__ WgT,
    const float* __restrict__ bg, float* __restrict__ gate)
{
  int wid = threadIdx.x >> 6, lane = threadIdx.x & 63;
  int l15 = lane & 15, lh = lane >> 4;
  int r0 = (blockIdx.x * 4 + wid) * 16;
  f32x4 acc = {};
  const __hip_bfloat16* arow = emb + (size_t)(r0 + l15) * D_DIM + lh * 8;
  const __hip_bfloat16* brow = WgT + (size_t)l15 * D_DIM + lh * 8;
#pragma unroll 4
  for (int k = 0; k < D_DIM; k += 32) {
    bf16x8 af = *reinterpret_cast<const bf16x8*>(arow + k);
    bf16x8 bf = *reinterpret_cast<const bf16x8*>(brow + k);
    acc = __builtin_amdgcn_mfma_f32_16x16x32_bf16(af, bf, acc, 0, 0, 0);
  }
  int t = l15 >> 3, e = l15 & 7;
  float bv = bg[t * E_EXP + e];
#pragma unroll
  for (int r = 0; r < 4; ++r) {
    float lg = acc[r] + bv;
    float m = lg;
    m = fmaxf(m, __shfl_xor(m, 1));
    m = fmaxf(m, __shfl_xor(m, 2));
    m = fmaxf(m, __shfl_xor(m, 4));
    float ex = expf(lg - m);
    float s = ex;
    s += __shfl_xor(s, 1);
    s += __shfl_xor(s, 2);
    s += __shfl_xor(s, 4);
    int row = r0 + lh * 4 + r;
    gate[((size_t)t * B_SZ + row) * E_EXP + e] = ex / s;
  }
}

// ---------------- bf16 MFMA GEMM: C[e] = relu(A[e] (MxK) * BT[e]^T (NxK) + bias[e]) -> bf16
// m97 structure: 128x128 tile, BK=32, 4 waves of 64x64, global_load_lds width 16.
template <int BM, int BN, int BK>
__global__ __launch_bounds__(256) void gemm_bt_bias_relu(
    const __hip_bfloat16* __restrict__ A, size_t strideAe,
    const __hip_bfloat16* __restrict__ BT,
    const float* __restrict__ bias,
    __hip_bfloat16* __restrict__ C,
    int M, int N, int K)
{
  int e = blockIdx.z;
  const __hip_bfloat16* Ap = A + strideAe * (size_t)e;
  const __hip_bfloat16* Bp = BT + (size_t)e * N * K;
  const float* bp = bias + (size_t)e * N;
  __hip_bfloat16* Cp = C + (size_t)e * M * N;
  int bm0 = blockIdx.x * BM, bn0 = blockIdx.y * BN;

  __shared__ __align__(16) __hip_bfloat16 As[BM * BK]; // 8 KB
  __shared__ __align__(16) __hip_bfloat16 Bs[BN * BK]; // 8 KB

  int tid = threadIdx.x;
  int wid = tid >> 6, lane = tid & 63;
  int l15 = lane & 15, lh = lane >> 4;
  int wm = (wid >> 1) * 64, wn = (wid & 1) * 64;

  f32x4 acc[4][4] = {};

  int r0 = tid >> 2;        // staging row (0..63)
  int c0e = (tid & 3) * 8;  // staging col (elements)
  char* AsB = (char*)As;
  char* BsB = (char*)Bs;
  int ldsOff = wid * 1024;  // wave-uniform LDS base; HW adds lane*16

  for (int kt = 0; kt < K; kt += BK) {
    __syncthreads();
#pragma unroll
    for (int j = 0; j < 2; ++j) {
      gload_lds16(Ap + (size_t)(bm0 + r0 + j * 64) * K + kt + c0e, AsB + ldsOff + j * 4096);
      gload_lds16(Bp + (size_t)(bn0 + r0 + j * 64) * K + kt + c0e, BsB + ldsOff + j * 4096);
    }
    __syncthreads();
    bf16x8 af[4], bf[4];
#pragma unroll
    for (int mi = 0; mi < 4; ++mi)
      af[mi] = *reinterpret_cast<const bf16x8*>(&As[(wm + mi * 16 + l15) * BK + lh * 8]);
#pragma unroll
    for (int nj = 0; nj < 4; ++nj)
      bf[nj] = *reinterpret_cast<const bf16x8*>(&Bs[(wn + nj * 16 + l15) * BK + lh * 8]);
#pragma unroll
    for (int mi = 0; mi < 4; ++mi)
#pragma unroll
      for (int nj = 0; nj < 4; ++nj)
        acc[mi][nj] = __builtin_amdgcn_mfma_f32_16x16x32_bf16(af[mi], bf[nj], acc[mi][nj], 0, 0, 0);
  }

#pragma unroll
  for (int nj = 0; nj < 4; ++nj) {
    int col = bn0 + wn + nj * 16 + l15;
    float bv = bp[col];
#pragma unroll
    for (int mi = 0; mi < 4; ++mi) {
      int rb = bm0 + wm + mi * 16 + lh * 4;
#pragma unroll
      for (int r = 0; r < 4; ++r) {
        float v = acc[mi][nj][r] + bv;
        v = fmaxf(v, 0.f);
        Cp[(size_t)(rb + r) * N + col] = __float2bfloat16(v);
      }
    }
  }
}

// ---------------- gate-combine + tower MLPs + sigmoid (16 batch rows per block)
#define TB 16
__global__ __launch_bounds__(256) void combine_tower(
    const float* __restrict__ gate, const __hip_bfloat16* __restrict__ fea,
    const float* __restrict__ Wt1, const float* __restrict__ bt1,
    const float* __restrict__ Wt2, const float* __restrict__ bt2,
    const float* __restrict__ Wt3, const float* __restrict__ bt3,
    float* __restrict__ out)
{
  int t = blockIdx.y;
  int b0 = blockIdx.x * TB;
  int tid = threadIdx.x;
  __shared__ float gs[TB][E_EXP];
  __shared__ float tf[TB][BOT1];
  __shared__ float h1[TB][TOW0];
  __shared__ float h2[TB][TOW1];
  if (tid < TB * E_EXP) {
    int bl = tid >> 3, e = tid & 7;
    gs[bl][e] = gate[((size_t)t * B_SZ + b0 + bl) * E_EXP + e];
  }
  __syncthreads();
  // task_fea = sum_e gate * fea
  for (int i = tid; i < TB * BOT1; i += 256) {
    int bl = i >> 8, o = i & 255;
    float s = 0.f;
#pragma unroll
    for (int e = 0; e < E_EXP; ++e)
      s = fmaf(gs[bl][e], __bfloat162float(fea[((size_t)e * B_SZ + b0 + bl) * BOT1 + o]), s);
    tf[bl][o] = s;
  }
  __syncthreads();
  // tower layer 1: 256 -> 128
  {
    int h = tid & 127, half = tid >> 7;
    float a[8] = {0, 0, 0, 0, 0, 0, 0, 0};
    for (int d = 0; d < BOT1; ++d) {
      float w = Wt1[((size_t)t * BOT1 + d) * TOW0 + h];
#pragma unroll
      for (int q = 0; q < 8; ++q) a[q] = fmaf(w, tf[half * 8 + q][d], a[q]);
    }
    float bv = bt1[t * TOW0 + h];
#pragma unroll
    for (int q = 0; q < 8; ++q) h1[half * 8 + q][h] = fmaxf(a[q] + bv, 0.f);
  }
  __syncthreads();
  // tower layer 2: 128 -> 64
  {
    int h = tid & 63, qt = tid >> 6;
    float a[4] = {0, 0, 0, 0};
    for (int d = 0; d < TOW0; ++d) {
      float w = Wt2[((size_t)t * TOW0 + d) * TOW1 + h];
#pragma unroll
      for (int q = 0; q < 4; ++q) a[q] = fmaf(w, h1[qt * 4 + q][d], a[q]);
    }
    float bv = bt2[t * TOW1 + h];
#pragma unroll
    for (int q = 0; q < 4; ++q) h2[qt * 4 + q][h] = fmaxf(a[q] + bv, 0.f);
  }
  __syncthreads();
  // tower layer 3: 64 -> 1 + sigmoid
  {
    int l16 = tid & 15, bl = tid >> 4;
    float p = 0.f;
#pragma unroll
    for (int d = l16; d < TOW1; d += 16) p = fmaf(h2[bl][d], Wt3[t * TOW1 + d], p);
#pragma unroll
    for (int o = 8; o; o >>= 1) p += __shfl_down(p, o, 16);
    if (l16 == 0) {
      float lg = p + bt3[t];
      out[(size_t)t * B_SZ + b0 + bl] = 1.f / (1.f + expf(-lg));
    }
  }
}

extern "C" void kernel_launch(void* const* d_in, const int* in_sizes, int n_in,
                              void* d_out, int out_size, void* d_ws, size_t ws_size,
                              hipStream_t stream) {
  const int* cat = (const int*)d_in[0];
  const float* numx = (const float*)d_in[1];
  const int* offsets = (const int*)d_in[2];
  const float* W_emb = (const float*)d_in[3];
  const float* Wn = (const float*)d_in[4];
  const float* bnv = (const float*)d_in[5];
  const float* We1 = (const float*)d_in[6];
  const float* be1 = (const float*)d_in[7];
  const float* We2 = (const float*)d_in[8];
  const float* be2 = (const float*)d_in[9];
  const float* Wg = (const float*)d_in[10];
  const float* bg = (const float*)d_in[11];
  const float* Wt1 = (const float*)d_in[12];
  const float* bt1 = (const float*)d_in[13];
  const float* Wt2 = (const float*)d_in[14];
  const float* bt2 = (const float*)d_in[15];
  const float* Wt3 = (const float*)d_in[16];
  const float* bt3 = (const float*)d_in[17];
  float* out = (float*)d_out;

  char* ws = (char*)d_ws;
  size_t off = 0;
  auto alloc = [&](size_t bytes) {
    char* p = ws + off;
    off += (bytes + 255) & ~(size_t)255;
    return p;
  };
  __hip_bfloat16* emb  = (__hip_bfloat16*)alloc((size_t)B_SZ * D_DIM * 2);
  __hip_bfloat16* We1T = (__hip_bfloat16*)alloc((size_t)E_EXP * BOT0 * D_DIM * 2);
  __hip_bfloat16* We2T = (__hip_bfloat16*)alloc((size_t)E_EXP * BOT1 * BOT0 * 2);
  __hip_bfloat16* H    = (__hip_bfloat16*)alloc((size_t)E_EXP * B_SZ * BOT0 * 2);
  __hip_bfloat16* fea  = (__hip_bfloat16*)alloc((size_t)E_EXP * B_SZ * BOT1 * 2);
  float* gate = (float*)alloc((size_t)T_TASK * B_SZ * E_EXP * 4);
  __hip_bfloat16* WgT  = (__hip_bfloat16*)alloc((size_t)T_TASK * E_EXP * D_DIM * 2);

  // 1. weight transpose/convert
  transpose_to_bf16<<<dim3(BOT0 / 32, D_DIM / 32, E_EXP), 256, 0, stream>>>(We1, We1T, D_DIM, BOT0);
  transpose_to_bf16<<<dim3(BOT1 / 32, BOT0 / 32, E_EXP), 256, 0, stream>>>(We2, We2T, BOT0, BOT1);
  wg_transpose<<<dim3(T_TASK * E_EXP * D_DIM / 256), 256, 0, stream>>>(Wg, WgT);

  // 2. embedding gather + numeric linear
  embed_convert<<<dim3(B_SZ / 4), 256, 0, stream>>>(cat, numx, offsets, W_emb, Wn, bnv, emb);

  // 3. gate GEMM + softmax
  gate_mfma<<<dim3(B_SZ / 64), 256, 0, stream>>>(emb, WgT, bg, gate);

  // 4. expert layer 1: (4096x1728)x(1728x512) x8 -> H
  gemm_bt_bias_relu<128, 128, 32><<<dim3(B_SZ / 128, BOT0 / 128, E_EXP), 256, 0, stream>>>(
      emb, (size_t)0, We1T, be1, H, B_SZ, BOT0, D_DIM);

  // 5. expert layer 2: (4096x512)x(512x256) x8 -> fea
  gemm_bt_bias_relu<128, 128, 32><<<dim3(B_SZ / 128, BOT1 / 128, E_EXP), 256, 0, stream>>>(
      H, (size_t)B_SZ * BOT0, We2T, be2, fea, B_SZ, BOT1, BOT0);

  // 6. gated combine + towers + sigmoid
  combine_tower<<<dim3(B_SZ / TB, T_TASK), 256, 0, stream>>>(
      gate, fea, Wt1, bt1, Wt2, bt2, Wt3, bt3, out);
}

// Round 3
// 148.834 us; speedup vs baseline: 2.3102x; 1.1689x over previous
//
#include <hip/hip_runtime.h>
#include <hip/hip_bf16.h>

#define B_SZ 4096
#define F_CAT 26
#define NUM_N 13
#define ED 64
#define D_DIM 1728   // 27*64
#define E_EXP 8
#define T_TASK 2
#define BOT0 512
#define BOT1 256
#define TOW0 128
#define TOW1 64

typedef __bf16 bf16x8 __attribute__((ext_vector_type(8)));
typedef float f32x4 __attribute__((ext_vector_type(4)));

__device__ __forceinline__ void gload_lds16(const void* g, void* l) {
  __builtin_amdgcn_global_load_lds(
      (const __attribute__((address_space(1))) void*)g,
      (__attribute__((address_space(3))) void*)l, 16, 0, 0);
}

#define BAR() do { asm volatile("" ::: "memory"); __builtin_amdgcn_s_barrier(); asm volatile("" ::: "memory"); } while (0)
#define LGKM0() do { asm volatile("s_waitcnt lgkmcnt(0)" ::: "memory"); __builtin_amdgcn_sched_barrier(0); } while (0)

// ---------------- transpose + fp32->bf16 convert: in (R,C) f32 -> out (C,R) bf16, batched over z
__global__ __launch_bounds__(256) void transpose_to_bf16(
    const float* __restrict__ in, __hip_bfloat16* __restrict__ out, int R, int C)
{
  __shared__ float tile[32][33];
  const float* inp = in + (size_t)blockIdx.z * R * C;
  __hip_bfloat16* outp = out + (size_t)blockIdx.z * R * C;
  int c0 = blockIdx.x * 32, r0 = blockIdx.y * 32;
  int tx = threadIdx.x & 31, ty = threadIdx.x >> 5; // 32 x 8
#pragma unroll
  for (int i = 0; i < 32; i += 8)
    tile[ty + i][tx] = inp[(size_t)(r0 + ty + i) * C + c0 + tx];
  __syncthreads();
#pragma unroll
  for (int i = 0; i < 32; i += 8)
    outp[(size_t)(c0 + ty + i) * R + r0 + tx] = __float2bfloat16(tile[tx][ty + i]);
}

// ---------------- Wg (T,D,E) f32 -> WgT (T*E, D) bf16
__global__ __launch_bounds__(256) void wg_transpose(
    const float* __restrict__ Wg, __hip_bfloat16* __restrict__ WgT)
{
  int i = blockIdx.x * 256 + threadIdx.x; // over 16*1728
  int n = i / D_DIM, d = i - n * D_DIM;
  int t = n >> 3, e = n & 7;
  WgT[i] = __float2bfloat16(Wg[((size_t)t * D_DIM + d) * E_EXP + e]);
}

// ---------------- embedding gather + numeric linear -> emb bf16 (4 batch rows / block)
__global__ __launch_bounds__(256) void embed_convert(
    const int* __restrict__ cat, const float* __restrict__ numx,
    const int* __restrict__ offsets, const float* __restrict__ W_emb,
    const float* __restrict__ Wn, const float* __restrict__ bnum,
    __hip_bfloat16* __restrict__ emb)
{
  const int UNITS = 27 * 16; // float4 units per row
  int b0 = blockIdx.x * 4;
  for (int idx = threadIdx.x; idx < 4 * UNITS; idx += 256) {
    int r = idx / UNITS, u = idx - r * UNITS;
    int f = u >> 4, d4 = (u & 15) * 4;
    int b = b0 + r;
    float4 v;
    if (f < F_CAT) {
      int row = cat[(size_t)b * F_CAT + f] + offsets[f];
      v = *reinterpret_cast<const float4*>(&W_emb[(size_t)row * ED + d4]);
    } else {
      float a0 = bnum[d4], a1 = bnum[d4 + 1], a2 = bnum[d4 + 2], a3 = bnum[d4 + 3];
#pragma unroll
      for (int n = 0; n < NUM_N; ++n) {
        float x = numx[(size_t)b * NUM_N + n];
        const float* wr = &Wn[n * ED + d4];
        a0 = fmaf(x, wr[0], a0);
        a1 = fmaf(x, wr[1], a1);
        a2 = fmaf(x, wr[2], a2);
        a3 = fmaf(x, wr[3], a3);
      }
      v = make_float4(a0, a1, a2, a3);
    }
    union { __hip_bfloat16 h[4]; uint2 u2; } pk;
    pk.h[0] = __float2bfloat16(v.x);
    pk.h[1] = __float2bfloat16(v.y);
    pk.h[2] = __float2bfloat16(v.z);
    pk.h[3] = __float2bfloat16(v.w);
    *reinterpret_cast<uint2*>(&emb[(size_t)b * D_DIM + f * ED + d4]) = pk.u2;
  }
}

// ---------------- gate GEMM (M=4096, N=16, K=1728) via MFMA + fused per-task softmax
__global__ __launch_bounds__(256) void gate_mfma(
    const __hip_bfloat16* __restrict__ emb, const __hip_bfloat16* __restrict__ WgT,
    const float* __restrict__ bg, float* __restrict__ gate)
{
  int wid = threadIdx.x >> 6, lane = threadIdx.x & 63;
  int l15 = lane & 15, lh = lane >> 4;
  int r0 = (blockIdx.x * 4 + wid) * 16;
  f32x4 acc = {};
  const __hip_bfloat16* arow = emb + (size_t)(r0 + l15) * D_DIM + lh * 8;
  const __hip_bfloat16* brow = WgT + (size_t)l15 * D_DIM + lh * 8;
#pragma unroll 4
  for (int k = 0; k < D_DIM; k += 32) {
    bf16x8 af = *reinterpret_cast<const bf16x8*>(arow + k);
    bf16x8 bf = *reinterpret_cast<const bf16x8*>(brow + k);
    acc = __builtin_amdgcn_mfma_f32_16x16x32_bf16(af, bf, acc, 0, 0, 0);
  }
  int t = l15 >> 3, e = l15 & 7;
  float bv = bg[t * E_EXP + e];
#pragma unroll
  for (int r = 0; r < 4; ++r) {
    float lg = acc[r] + bv;
    float m = lg;
    m = fmaxf(m, __shfl_xor(m, 1));
    m = fmaxf(m, __shfl_xor(m, 2));
    m = fmaxf(m, __shfl_xor(m, 4));
    float ex = expf(lg - m);
    float s = ex;
    s += __shfl_xor(s, 1);
    s += __shfl_xor(s, 2);
    s += __shfl_xor(s, 4);
    int row = r0 + lh * 4 + r;
    gate[((size_t)t * B_SZ + row) * E_EXP + e] = ex / s;
  }
}

// =========================================================================
// 8-phase 256x256 BK=64 bf16 MFMA GEMM (m201-style schedule, plain HIP).
// 8 waves (2M x 4N), per-wave C = 128x64. Double-buffered LDS, slab-granular
// staging, counted vmcnt(4) once per K-tile (never 0 in loop).
// LDS map: A: [buf2][slab2][256 rows][64B], B same at +64KB. Total 128 KiB.
// Swizzle (both sides): slot' = slot ^ ((row>>2)&3)  -> conflict-free b128.
// =========================================================================
__device__ __forceinline__ bf16x8 fragld(const char* slab, int R, int lh) {
  int slot = lh ^ ((R >> 2) & 3);
  return *reinterpret_cast<const bf16x8*>(slab + R * 64 + slot * 16);
}

__device__ __forceinline__ void stage_unit(
    const __hip_bfloat16* __restrict__ gmat, int ld, int rowBase, int kelem,
    char* ldsSlab, int wid, int lane)
{
#pragma unroll
  for (int j = 0; j < 2; ++j) {
    int X = (wid << 10) + (lane << 4) + (j << 13);
    int row = X >> 6;
    int slot = (X >> 4) & 3;
    int ss = slot ^ ((row >> 2) & 3);
    gload_lds16(gmat + (size_t)(rowBase + row) * ld + kelem + ss * 8,
                ldsSlab + (wid << 10) + (j << 13));
  }
}

__device__ __forceinline__ void mfma16(const bf16x8* a, const bf16x8* b, f32x4 (*accRows)[4]) {
#pragma unroll
  for (int i = 0; i < 4; ++i)
#pragma unroll
    for (int j = 0; j < 4; ++j)
      accRows[i][j] = __builtin_amdgcn_mfma_f32_16x16x32_bf16(a[i], b[j], accRows[i][j], 0, 0, 0);
}

__global__ __launch_bounds__(512, 2) void gemm8p(
    const __hip_bfloat16* __restrict__ A, size_t strideAe,
    const __hip_bfloat16* __restrict__ BT,
    const float* __restrict__ bias,
    __hip_bfloat16* __restrict__ C,
    int M, int N, int K)
{
  extern __shared__ char smem[];
  int e = blockIdx.z;
  const __hip_bfloat16* Ap = A + strideAe * (size_t)e;
  const __hip_bfloat16* Bp = BT + (size_t)e * N * K;
  const float* bp = bias + (size_t)e * N;
  __hip_bfloat16* Cp = C + (size_t)e * M * N;
  int bm0 = blockIdx.x * 256, bn0 = blockIdx.y * 256;

  int tid = threadIdx.x;
  int wid = tid >> 6, lane = tid & 63;
  int l15 = lane & 15, lh = lane >> 4;
  int wm = wid >> 2, wn = wid & 3;
  int wrow = wm * 128, wcol = wn * 64;

  auto Aslab = [&](int buf, int s) { return smem + ((buf * 2 + s) << 14); };
  auto Bslab = [&](int buf, int s) { return smem + 65536 + ((buf * 2 + s) << 14); };

  f32x4 acc[8][4] = {};
  int NT = K >> 6;

  // ---- prologue: tile0 all 4 slabs + tile1 k0 slabs (12 gloads / thread)
  stage_unit(Ap, K, bm0, 0,  Aslab(0, 0), wid, lane);
  stage_unit(Bp, K, bn0, 0,  Bslab(0, 0), wid, lane);
  stage_unit(Ap, K, bm0, 32, Aslab(0, 1), wid, lane);
  stage_unit(Bp, K, bn0, 32, Bslab(0, 1), wid, lane);
  stage_unit(Ap, K, bm0, 64, Aslab(1, 0), wid, lane);
  stage_unit(Bp, K, bn0, 64, Bslab(1, 0), wid, lane);
  asm volatile("s_waitcnt vmcnt(4)" ::: "memory");
  BAR();

  for (int T = 0; T < NT; ++T) {
    int cur = T & 1;
    int t1 = (T + 1 < NT) ? T + 1 : NT - 1;
    int t2 = (T + 2 < NT) ? T + 2 : NT - 1;
    const char* As0 = Aslab(cur, 0); const char* As1 = Aslab(cur, 1);
    const char* Bs0 = Bslab(cur, 0); const char* Bs1 = Bslab(cur, 1);
    bf16x8 a[4], b[4];

    // ---- p0: kk=0, rows 0-63 (per wave); stage (T+1, A-k1)
#pragma unroll
    for (int i = 0; i < 4; ++i) a[i] = fragld(As0, wrow + i * 16 + l15, lh);
#pragma unroll
    for (int j = 0; j < 4; ++j) b[j] = fragld(Bs0, wcol + j * 16 + l15, lh);
    stage_unit(Ap, K, bm0, t1 * 64 + 32, Aslab((T + 1) & 1, 1), wid, lane);
    BAR();
    LGKM0();
    __builtin_amdgcn_s_setprio(1);
    mfma16(a, b, acc);
    __builtin_amdgcn_s_setprio(0);
    BAR();

    // ---- p1: kk=0, rows 64-127; stage (T+1, B-k1)
#pragma unroll
    for (int i = 0; i < 4; ++i) a[i] = fragld(As0, wrow + 64 + i * 16 + l15, lh);
    stage_unit(Bp, K, bn0, t1 * 64 + 32, Bslab((T + 1) & 1, 1), wid, lane);
    BAR();
    LGKM0();
    __builtin_amdgcn_s_setprio(1);
    mfma16(a, b, acc + 4);
    __builtin_amdgcn_s_setprio(0);
    BAR();

    // ---- p2: kk=1, rows 0-63; stage (T+2, A-k0)
#pragma unroll
    for (int i = 0; i < 4; ++i) a[i] = fragld(As1, wrow + i * 16 + l15, lh);
#pragma unroll
    for (int j = 0; j < 4; ++j) b[j] = fragld(Bs1, wcol + j * 16 + l15, lh);
    stage_unit(Ap, K, bm0, t2 * 64, Aslab(T & 1, 0), wid, lane);
    BAR();
    LGKM0();
    __builtin_amdgcn_s_setprio(1);
    mfma16(a, b, acc);
    __builtin_amdgcn_s_setprio(0);
    BAR();

    // ---- p3: kk=1, rows 64-127; stage (T+2, B-k0); counted vmcnt once/tile
#pragma unroll
    for (int i = 0; i < 4; ++i) a[i] = fragld(As1, wrow + 64 + i * 16 + l15, lh);
    stage_unit(Bp, K, bn0, t2 * 64, Bslab(T & 1, 0), wid, lane);
    BAR();
    LGKM0();
    __builtin_amdgcn_s_setprio(1);
    mfma16(a, b, acc + 4);
    __builtin_amdgcn_s_setprio(0);
    asm volatile("s_waitcnt vmcnt(4)" ::: "memory");
    BAR();
  }

  // ---- epilogue: bias + relu + bf16 store
#pragma unroll
  for (int nj = 0; nj < 4; ++nj) {
    int col = bn0 + wcol + nj * 16 + l15;
    float bv = bp[col];
#pragma unroll
    for (int mi = 0; mi < 8; ++mi) {
      int rb = bm0 + wrow + mi * 16 + lh * 4;
#pragma unroll
      for (int r = 0; r < 4; ++r) {
        float v = acc[mi][nj][r] + bv;
        Cp[(size_t)(rb + r) * N + col] = __float2bfloat16(fmaxf(v, 0.f));
      }
    }
  }
}

// ---------------- gate-combine + tower MLPs + sigmoid (16 batch rows per block)
#define TB 16
__global__ __launch_bounds__(256) void combine_tower(
    const float* __restrict__ gate, const __hip_bfloat16* __restrict__ fea,
    const float* __restrict__ Wt1, const float* __restrict__ bt1,
    const float* __restrict__ Wt2, const float* __restrict__ bt2,
    const float* __restrict__ Wt3, const float* __restrict__ bt3,
    float* __restrict__ out)
{
  int t = blockIdx.y;
  int b0 = blockIdx.x * TB;
  int tid = threadIdx.x;
  __shared__ float gs[TB][E_EXP];
  __shared__ float tf[TB][BOT1];
  __shared__ float h1[TB][TOW0];
  __shared__ float h2[TB][TOW1];
  if (tid < TB * E_EXP) {
    int bl = tid >> 3, e = tid & 7;
    gs[bl][e] = gate[((size_t)t * B_SZ + b0 + bl) * E_EXP + e];
  }
  __syncthreads();
  // task_fea = sum_e gate * fea
  for (int i = tid; i < TB * BOT1; i += 256) {
    int bl = i >> 8, o = i & 255;
    float s = 0.f;
#pragma unroll
    for (int e = 0; e < E_EXP; ++e)
      s = fmaf(gs[bl][e], __bfloat162float(fea[((size_t)e * B_SZ + b0 + bl) * BOT1 + o]), s);
    tf[bl][o] = s;
  }
  __syncthreads();
  // tower layer 1: 256 -> 128
  {
    int h = tid & 127, half = tid >> 7;
    float a[8] = {0, 0, 0, 0, 0, 0, 0, 0};
    for (int d = 0; d < BOT1; ++d) {
      float w = Wt1[((size_t)t * BOT1 + d) * TOW0 + h];
#pragma unroll
      for (int q = 0; q < 8; ++q) a[q] = fmaf(w, tf[half * 8 + q][d], a[q]);
    }
    float bv = bt1[t * TOW0 + h];
#pragma unroll
    for (int q = 0; q < 8; ++q) h1[half * 8 + q][h] = fmaxf(a[q] + bv, 0.f);
  }
  __syncthreads();
  // tower layer 2: 128 -> 64
  {
    int h = tid & 63, qt = tid >> 6;
    float a[4] = {0, 0, 0, 0};
    for (int d = 0; d < TOW0; ++d) {
      float w = Wt2[((size_t)t * TOW0 + d) * TOW1 + h];
#pragma unroll
      for (int q = 0; q < 4; ++q) a[q] = fmaf(w, h1[qt * 4 + q][d], a[q]);
    }
    float bv = bt2[t * TOW1 + h];
#pragma unroll
    for (int q = 0; q < 4; ++q) h2[qt * 4 + q][h] = fmaxf(a[q] + bv, 0.f);
  }
  __syncthreads();
  // tower layer 3: 64 -> 1 + sigmoid
  {
    int l16 = tid & 15, bl = tid >> 4;
    float p = 0.f;
#pragma unroll
    for (int d = l16; d < TOW1; d += 16) p = fmaf(h2[bl][d], Wt3[t * TOW1 + d], p);
#pragma unroll
    for (int o = 8; o; o >>= 1) p += __shfl_down(p, o, 16);
    if (l16 == 0) {
      float lg = p + bt3[t];
      out[(size_t)t * B_SZ + b0 + bl] = 1.f / (1.f + expf(-lg));
    }
  }
}

extern "C" void kernel_launch(void* const* d_in, const int* in_sizes, int n_in,
                              void* d_out, int out_size, void* d_ws, size_t ws_size,
                              hipStream_t stream) {
  const int* cat = (const int*)d_in[0];
  const float* numx = (const float*)d_in[1];
  const int* offsets = (const int*)d_in[2];
  const float* W_emb = (const float*)d_in[3];
  const float* Wn = (const float*)d_in[4];
  const float* bnv = (const float*)d_in[5];
  const float* We1 = (const float*)d_in[6];
  const float* be1 = (const float*)d_in[7];
  const float* We2 = (const float*)d_in[8];
  const float* be2 = (const float*)d_in[9];
  const float* Wg = (const float*)d_in[10];
  const float* bg = (const float*)d_in[11];
  const float* Wt1 = (const float*)d_in[12];
  const float* bt1 = (const float*)d_in[13];
  const float* Wt2 = (const float*)d_in[14];
  const float* bt2 = (const float*)d_in[15];
  const float* Wt3 = (const float*)d_in[16];
  const float* bt3 = (const float*)d_in[17];
  float* out = (float*)d_out;

  char* ws = (char*)d_ws;
  size_t off = 0;
  auto alloc = [&](size_t bytes) {
    char* p = ws + off;
    off += (bytes + 255) & ~(size_t)255;
    return p;
  };
  __hip_bfloat16* emb  = (__hip_bfloat16*)alloc((size_t)B_SZ * D_DIM * 2);
  __hip_bfloat16* We1T = (__hip_bfloat16*)alloc((size_t)E_EXP * BOT0 * D_DIM * 2);
  __hip_bfloat16* We2T = (__hip_bfloat16*)alloc((size_t)E_EXP * BOT1 * BOT0 * 2);
  __hip_bfloat16* H    = (__hip_bfloat16*)alloc((size_t)E_EXP * B_SZ * BOT0 * 2);
  __hip_bfloat16* fea  = (__hip_bfloat16*)alloc((size_t)E_EXP * B_SZ * BOT1 * 2);
  float* gate = (float*)alloc((size_t)T_TASK * B_SZ * E_EXP * 4);
  __hip_bfloat16* WgT  = (__hip_bfloat16*)alloc((size_t)T_TASK * E_EXP * D_DIM * 2);

  // opt-in to 128 KiB dynamic LDS for the 8-phase GEMM (host-side, capture-safe)
  hipFuncSetAttribute((const void*)gemm8p,
                      hipFuncAttributeMaxDynamicSharedMemorySize, 131072);

  // 1. weight transpose/convert
  transpose_to_bf16<<<dim3(BOT0 / 32, D_DIM / 32, E_EXP), 256, 0, stream>>>(We1, We1T, D_DIM, BOT0);
  transpose_to_bf16<<<dim3(BOT1 / 32, BOT0 / 32, E_EXP), 256, 0, stream>>>(We2, We2T, BOT0, BOT1);
  wg_transpose<<<dim3(T_TASK * E_EXP * D_DIM / 256), 256, 0, stream>>>(Wg, WgT);

  // 2. embedding gather + numeric linear
  embed_convert<<<dim3(B_SZ / 4), 256, 0, stream>>>(cat, numx, offsets, W_emb, Wn, bnv, emb);

  // 3. gate GEMM + softmax
  gate_mfma<<<dim3(B_SZ / 64), 256, 0, stream>>>(emb, WgT, bg, gate);

  // 4. expert layer 1: (4096x1728)x(1728x512) x8 -> H   [grid 16x2x8 = 256 blocks = 1/CU]
  gemm8p<<<dim3(B_SZ / 256, BOT0 / 256, E_EXP), 512, 131072, stream>>>(
      emb, (size_t)0, We1T, be1, H, B_SZ, BOT0, D_DIM);

  // 5. expert layer 2: (4096x512)x(512x256) x8 -> fea   [grid 16x1x8 = 128 blocks]
  gemm8p<<<dim3(B_SZ / 256, BOT1 / 256, E_EXP), 512, 131072, stream>>>(
      H, (size_t)B_SZ * BOT0, We2T, be2, fea, B_SZ, BOT1, BOT0);

  // 6. gated combine + towers + sigmoid
  combine_tower<<<dim3(B_SZ / TB, T_TASK), 256, 0, stream>>>(
      gate, fea, Wt1, bt1, Wt2, bt2, Wt3, bt3, out);
}

// Round 4
// 139.986 us; speedup vs baseline: 2.4562x; 1.0632x over previous
//
#include <hip/hip_runtime.h>
#include <hip/hip_bf16.h>

#define B_SZ 4096
#define F_CAT 26
#define NUM_N 13
#define ED 64
#define D_DIM 1728   // 27*64
#define E_EXP 8
#define T_TASK 2
#define BOT0 512
#define BOT1 256
#define TOW0 128
#define TOW1 64

typedef __bf16 bf16x8 __attribute__((ext_vector_type(8)));
typedef float f32x4 __attribute__((ext_vector_type(4)));

__device__ __forceinline__ void gload_lds16(const void* g, void* l) {
  __builtin_amdgcn_global_load_lds(
      (const __attribute__((address_space(1))) void*)g,
      (__attribute__((address_space(3))) void*)l, 16, 0, 0);
}

#define BAR() do { asm volatile("" ::: "memory"); __builtin_amdgcn_s_barrier(); asm volatile("" ::: "memory"); } while (0)
#define LGKM0() do { asm volatile("s_waitcnt lgkmcnt(0)" ::: "memory"); __builtin_amdgcn_sched_barrier(0); } while (0)

// ---------------- transpose + fp32->bf16 convert: in (R,C) f32 -> out (C,R) bf16, batched over z
__global__ __launch_bounds__(256) void transpose_to_bf16(
    const float* __restrict__ in, __hip_bfloat16* __restrict__ out, int R, int C)
{
  __shared__ float tile[32][33];
  const float* inp = in + (size_t)blockIdx.z * R * C;
  __hip_bfloat16* outp = out + (size_t)blockIdx.z * R * C;
  int c0 = blockIdx.x * 32, r0 = blockIdx.y * 32;
  int tx = threadIdx.x & 31, ty = threadIdx.x >> 5; // 32 x 8
#pragma unroll
  for (int i = 0; i < 32; i += 8)
    tile[ty + i][tx] = inp[(size_t)(r0 + ty + i) * C + c0 + tx];
  __syncthreads();
#pragma unroll
  for (int i = 0; i < 32; i += 8)
    outp[(size_t)(c0 + ty + i) * R + r0 + tx] = __float2bfloat16(tile[tx][ty + i]);
}

// ---------------- Wg (T,D,E) f32 -> WgT (T*E, D) bf16
__global__ __launch_bounds__(256) void wg_transpose(
    const float* __restrict__ Wg, __hip_bfloat16* __restrict__ WgT)
{
  int i = blockIdx.x * 256 + threadIdx.x; // over 16*1728
  int n = i / D_DIM, d = i - n * D_DIM;
  int t = n >> 3, e = n & 7;
  WgT[i] = __float2bfloat16(Wg[((size_t)t * D_DIM + d) * E_EXP + e]);
}

// ---------------- embedding gather + numeric linear -> emb bf16 (4 batch rows / block)
__global__ __launch_bounds__(256) void embed_convert(
    const int* __restrict__ cat, const float* __restrict__ numx,
    const int* __restrict__ offsets, const float* __restrict__ W_emb,
    const float* __restrict__ Wn, const float* __restrict__ bnum,
    __hip_bfloat16* __restrict__ emb)
{
  const int UNITS = 27 * 16; // float4 units per row
  int b0 = blockIdx.x * 4;
  for (int idx = threadIdx.x; idx < 4 * UNITS; idx += 256) {
    int r = idx / UNITS, u = idx - r * UNITS;
    int f = u >> 4, d4 = (u & 15) * 4;
    int b = b0 + r;
    float4 v;
    if (f < F_CAT) {
      int row = cat[(size_t)b * F_CAT + f] + offsets[f];
      v = *reinterpret_cast<const float4*>(&W_emb[(size_t)row * ED + d4]);
    } else {
      float a0 = bnum[d4], a1 = bnum[d4 + 1], a2 = bnum[d4 + 2], a3 = bnum[d4 + 3];
#pragma unroll
      for (int n = 0; n < NUM_N; ++n) {
        float x = numx[(size_t)b * NUM_N + n];
        const float* wr = &Wn[n * ED + d4];
        a0 = fmaf(x, wr[0], a0);
        a1 = fmaf(x, wr[1], a1);
        a2 = fmaf(x, wr[2], a2);
        a3 = fmaf(x, wr[3], a3);
      }
      v = make_float4(a0, a1, a2, a3);
    }
    union { __hip_bfloat16 h[4]; uint2 u2; } pk;
    pk.h[0] = __float2bfloat16(v.x);
    pk.h[1] = __float2bfloat16(v.y);
    pk.h[2] = __float2bfloat16(v.z);
    pk.h[3] = __float2bfloat16(v.w);
    *reinterpret_cast<uint2*>(&emb[(size_t)b * D_DIM + f * ED + d4]) = pk.u2;
  }
}

// ---------------- gate GEMM (M=4096, N=16, K=1728) via MFMA + fused per-task softmax
__global__ __launch_bounds__(256) void gate_mfma(
    const __hip_bfloat16* __restrict__ emb, const __hip_bfloat16* __restrict__ WgT,
    const float* __restrict__ bg, float* __restrict__ gate)
{
  int wid = threadIdx.x >> 6, lane = threadIdx.x & 63;
  int l15 = lane & 15, lh = lane >> 4;
  int r0 = (blockIdx.x * 4 + wid) * 16;
  f32x4 acc = {};
  const __hip_bfloat16* arow = emb + (size_t)(r0 + l15) * D_DIM + lh * 8;
  const __hip_bfloat16* brow = WgT + (size_t)l15 * D_DIM + lh * 8;
#pragma unroll 4
  for (int k = 0; k < D_DIM; k += 32) {
    bf16x8 af = *reinterpret_cast<const bf16x8*>(arow + k);
    bf16x8 bf = *reinterpret_cast<const bf16x8*>(brow + k);
    acc = __builtin_amdgcn_mfma_f32_16x16x32_bf16(af, bf, acc, 0, 0, 0);
  }
  int t = l15 >> 3, e = l15 & 7;
  float bv = bg[t * E_EXP + e];
#pragma unroll
  for (int r = 0; r < 4; ++r) {
    float lg = acc[r] + bv;
    float m = lg;
    m = fmaxf(m, __shfl_xor(m, 1));
    m = fmaxf(m, __shfl_xor(m, 2));
    m = fmaxf(m, __shfl_xor(m, 4));
    float ex = expf(lg - m);
    float s = ex;
    s += __shfl_xor(s, 1);
    s += __shfl_xor(s, 2);
    s += __shfl_xor(s, 4);
    int row = r0 + lh * 4 + r;
    gate[((size_t)t * B_SZ + row) * E_EXP + e] = ex / s;
  }
}

// =========================================================================
// 8-phase 256x256 BK=64 bf16 MFMA GEMM. 8 waves (2M x 4N), per-wave C=128x64.
// Double-buffered LDS slabs (16 KB = 256 rows x 64 B, split by K-half),
// counted vmcnt(4) once per K-tile. LDS swizzle = m201's st_16x32:
// byte ^= ((byte>>9)&1)<<5  ==>  slot ^= ((row>>3)&1)<<1, applied BOTH sides
// (pre-swizzled global source + swizzled ds_read). Epilogue: LDS-staged
// coalesced 16B stores (kills bf16 write amplification).
// =========================================================================
__device__ __forceinline__ bf16x8 fragld(const char* slab, int R, int lh) {
  int slot = lh ^ (((R >> 3) & 1) << 1);   // st_16x32
  return *reinterpret_cast<const bf16x8*>(slab + R * 64 + slot * 16);
}

__device__ __forceinline__ void stage_unit(
    const __hip_bfloat16* __restrict__ gmat, int ld, int rowBase, int kelem,
    char* ldsSlab, int wid, int lane)
{
#pragma unroll
  for (int j = 0; j < 2; ++j) {
    int X = (wid << 10) + (lane << 4) + (j << 13);
    int row = X >> 6;
    int slot = (X >> 4) & 3;
    int ss = slot ^ (((row >> 3) & 1) << 1);  // st_16x32 (involution)
    gload_lds16(gmat + (size_t)(rowBase + row) * ld + kelem + ss * 8,
                ldsSlab + (wid << 10) + (j << 13));
  }
}

__device__ __forceinline__ void mfma16(const bf16x8* a, const bf16x8* b, f32x4 (*accRows)[4]) {
#pragma unroll
  for (int i = 0; i < 4; ++i)
#pragma unroll
    for (int j = 0; j < 4; ++j)
      accRows[i][j] = __builtin_amdgcn_mfma_f32_16x16x32_bf16(a[i], b[j], accRows[i][j], 0, 0, 0);
}

__global__ __launch_bounds__(512, 2) void gemm8p(
    const __hip_bfloat16* __restrict__ A, size_t strideAe,
    const __hip_bfloat16* __restrict__ BT,
    const float* __restrict__ bias,
    __hip_bfloat16* __restrict__ C,
    int M, int N, int K)
{
  extern __shared__ char smem[];
  int e = blockIdx.z;
  const __hip_bfloat16* Ap = A + strideAe * (size_t)e;
  const __hip_bfloat16* Bp = BT + (size_t)e * N * K;
  const float* bp = bias + (size_t)e * N;
  __hip_bfloat16* Cp = C + (size_t)e * M * N;
  int bm0 = blockIdx.x * 256, bn0 = blockIdx.y * 256;

  int tid = threadIdx.x;
  int wid = tid >> 6, lane = tid & 63;
  int l15 = lane & 15, lh = lane >> 4;
  int wm = wid >> 2, wn = wid & 3;
  int wrow = wm * 128, wcol = wn * 64;

  auto Aslab = [&](int buf, int s) { return smem + ((buf * 2 + s) << 14); };
  auto Bslab = [&](int buf, int s) { return smem + 65536 + ((buf * 2 + s) << 14); };

  f32x4 acc[8][4] = {};
  int NT = K >> 6;

  // ---- prologue: tile0 all 4 slabs + tile1 k0 slabs (12 gloads / thread)
  stage_unit(Ap, K, bm0, 0,  Aslab(0, 0), wid, lane);
  stage_unit(Bp, K, bn0, 0,  Bslab(0, 0), wid, lane);
  stage_unit(Ap, K, bm0, 32, Aslab(0, 1), wid, lane);
  stage_unit(Bp, K, bn0, 32, Bslab(0, 1), wid, lane);
  stage_unit(Ap, K, bm0, 64, Aslab(1, 0), wid, lane);
  stage_unit(Bp, K, bn0, 64, Bslab(1, 0), wid, lane);
  asm volatile("s_waitcnt vmcnt(4)" ::: "memory");
  BAR();

  for (int T = 0; T < NT; ++T) {
    int cur = T & 1;
    int t1 = (T + 1 < NT) ? T + 1 : NT - 1;
    int t2 = (T + 2 < NT) ? T + 2 : NT - 1;
    const char* As0 = Aslab(cur, 0); const char* As1 = Aslab(cur, 1);
    const char* Bs0 = Bslab(cur, 0); const char* Bs1 = Bslab(cur, 1);
    bf16x8 a[4], b[4];

    // ---- p0: kk=0, rows 0-63 (per wave); stage (T+1, A-k1)
#pragma unroll
    for (int i = 0; i < 4; ++i) a[i] = fragld(As0, wrow + i * 16 + l15, lh);
#pragma unroll
    for (int j = 0; j < 4; ++j) b[j] = fragld(Bs0, wcol + j * 16 + l15, lh);
    stage_unit(Ap, K, bm0, t1 * 64 + 32, Aslab((T + 1) & 1, 1), wid, lane);
    BAR();
    LGKM0();
    __builtin_amdgcn_s_setprio(1);
    mfma16(a, b, acc);
    __builtin_amdgcn_s_setprio(0);
    BAR();

    // ---- p1: kk=0, rows 64-127; stage (T+1, B-k1)
#pragma unroll
    for (int i = 0; i < 4; ++i) a[i] = fragld(As0, wrow + 64 + i * 16 + l15, lh);
    stage_unit(Bp, K, bn0, t1 * 64 + 32, Bslab((T + 1) & 1, 1), wid, lane);
    BAR();
    LGKM0();
    __builtin_amdgcn_s_setprio(1);
    mfma16(a, b, acc + 4);
    __builtin_amdgcn_s_setprio(0);
    BAR();

    // ---- p2: kk=1, rows 0-63; stage (T+2, A-k0)
#pragma unroll
    for (int i = 0; i < 4; ++i) a[i] = fragld(As1, wrow + i * 16 + l15, lh);
#pragma unroll
    for (int j = 0; j < 4; ++j) b[j] = fragld(Bs1, wcol + j * 16 + l15, lh);
    stage_unit(Ap, K, bm0, t2 * 64, Aslab(T & 1, 0), wid, lane);
    BAR();
    LGKM0();
    __builtin_amdgcn_s_setprio(1);
    mfma16(a, b, acc);
    __builtin_amdgcn_s_setprio(0);
    BAR();

    // ---- p3: kk=1, rows 64-127; stage (T+2, B-k0); counted vmcnt once/tile
#pragma unroll
    for (int i = 0; i < 4; ++i) a[i] = fragld(As1, wrow + 64 + i * 16 + l15, lh);
    stage_unit(Bp, K, bn0, t2 * 64, Bslab(T & 1, 0), wid, lane);
    BAR();
    LGKM0();
    __builtin_amdgcn_s_setprio(1);
    mfma16(a, b, acc + 4);
    __builtin_amdgcn_s_setprio(0);
    asm volatile("s_waitcnt vmcnt(4)" ::: "memory");
    BAR();
  }

  // ---- epilogue: drain tail prefetches (they land in LDS!), then stage C
  // through LDS as bf16 [256][256] and store fully coalesced (16 B/lane).
  asm volatile("s_waitcnt vmcnt(0)" ::: "memory");
  BAR();
  __hip_bfloat16* cs = (__hip_bfloat16*)smem;
#pragma unroll
  for (int nj = 0; nj < 4; ++nj) {
    int col = wcol + nj * 16 + l15;
    float bv = bp[bn0 + col];
#pragma unroll
    for (int mi = 0; mi < 8; ++mi) {
      int rb = wrow + mi * 16 + lh * 4;
#pragma unroll
      for (int r = 0; r < 4; ++r) {
        float v = acc[mi][nj][r] + bv;
        cs[(size_t)(rb + r) * 256 + col] = __float2bfloat16(fmaxf(v, 0.f));
      }
    }
  }
  BAR();
  {
    int rr = tid >> 5, c8 = (tid & 31) * 8; // 16 rows/pass, 32 x 16B per row
#pragma unroll
    for (int p = 0; p < 16; ++p) {
      int row = p * 16 + rr;
      *reinterpret_cast<uint4*>(&Cp[(size_t)(bm0 + row) * N + bn0 + c8]) =
          *reinterpret_cast<const uint4*>(&cs[(size_t)row * 256 + c8]);
    }
  }
}

// ---------------- gate-combine + tower MLPs + sigmoid (16 batch rows per block)
#define TB 16
__global__ __launch_bounds__(256) void combine_tower(
    const float* __restrict__ gate, const __hip_bfloat16* __restrict__ fea,
    const float* __restrict__ Wt1, const float* __restrict__ bt1,
    const float* __restrict__ Wt2, const float* __restrict__ bt2,
    const float* __restrict__ Wt3, const float* __restrict__ bt3,
    float* __restrict__ out)
{
  int t = blockIdx.y;
  int b0 = blockIdx.x * TB;
  int tid = threadIdx.x;
  __shared__ float gs[TB][E_EXP];
  __shared__ float tf[TB][BOT1];
  __shared__ float h1[TB][TOW0];
  __shared__ float h2[TB][TOW1];
  if (tid < TB * E_EXP) {
    int bl = tid >> 3, e = tid & 7;
    gs[bl][e] = gate[((size_t)t * B_SZ + b0 + bl) * E_EXP + e];
  }
  __syncthreads();
  // task_fea = sum_e gate * fea
  for (int i = tid; i < TB * BOT1; i += 256) {
    int bl = i >> 8, o = i & 255;
    float s = 0.f;
#pragma unroll
    for (int e = 0; e < E_EXP; ++e)
      s = fmaf(gs[bl][e], __bfloat162float(fea[((size_t)e * B_SZ + b0 + bl) * BOT1 + o]), s);
    tf[bl][o] = s;
  }
  __syncthreads();
  // tower layer 1: 256 -> 128
  {
    int h = tid & 127, half = tid >> 7;
    float a[8] = {0, 0, 0, 0, 0, 0, 0, 0};
    for (int d = 0; d < BOT1; ++d) {
      float w = Wt1[((size_t)t * BOT1 + d) * TOW0 + h];
#pragma unroll
      for (int q = 0; q < 8; ++q) a[q] = fmaf(w, tf[half * 8 + q][d], a[q]);
    }
    float bv = bt1[t * TOW0 + h];
#pragma unroll
    for (int q = 0; q < 8; ++q) h1[half * 8 + q][h] = fmaxf(a[q] + bv, 0.f);
  }
  __syncthreads();
  // tower layer 2: 128 -> 64
  {
    int h = tid & 63, qt = tid >> 6;
    float a[4] = {0, 0, 0, 0};
    for (int d = 0; d < TOW0; ++d) {
      float w = Wt2[((size_t)t * TOW0 + d) * TOW1 + h];
#pragma unroll
      for (int q = 0; q < 4; ++q) a[q] = fmaf(w, h1[qt * 4 + q][d], a[q]);
    }
    float bv = bt2[t * TOW1 + h];
#pragma unroll
    for (int q = 0; q < 4; ++q) h2[qt * 4 + q][h] = fmaxf(a[q] + bv, 0.f);
  }
  __syncthreads();
  // tower layer 3: 64 -> 1 + sigmoid
  {
    int l16 = tid & 15, bl = tid >> 4;
    float p = 0.f;
#pragma unroll
    for (int d = l16; d < TOW1; d += 16) p = fmaf(h2[bl][d], Wt3[t * TOW1 + d], p);
#pragma unroll
    for (int o = 8; o; o >>= 1) p += __shfl_down(p, o, 16);
    if (l16 == 0) {
      float lg = p + bt3[t];
      out[(size_t)t * B_SZ + b0 + bl] = 1.f / (1.f + expf(-lg));
    }
  }
}

extern "C" void kernel_launch(void* const* d_in, const int* in_sizes, int n_in,
                              void* d_out, int out_size, void* d_ws, size_t ws_size,
                              hipStream_t stream) {
  const int* cat = (const int*)d_in[0];
  const float* numx = (const float*)d_in[1];
  const int* offsets = (const int*)d_in[2];
  const float* W_emb = (const float*)d_in[3];
  const float* Wn = (const float*)d_in[4];
  const float* bnv = (const float*)d_in[5];
  const float* We1 = (const float*)d_in[6];
  const float* be1 = (const float*)d_in[7];
  const float* We2 = (const float*)d_in[8];
  const float* be2 = (const float*)d_in[9];
  const float* Wg = (const float*)d_in[10];
  const float* bg = (const float*)d_in[11];
  const float* Wt1 = (const float*)d_in[12];
  const float* bt1 = (const float*)d_in[13];
  const float* Wt2 = (const float*)d_in[14];
  const float* bt2 = (const float*)d_in[15];
  const float* Wt3 = (const float*)d_in[16];
  const float* bt3 = (const float*)d_in[17];
  float* out = (float*)d_out;

  char* ws = (char*)d_ws;
  size_t off = 0;
  auto alloc = [&](size_t bytes) {
    char* p = ws + off;
    off += (bytes + 255) & ~(size_t)255;
    return p;
  };
  __hip_bfloat16* emb  = (__hip_bfloat16*)alloc((size_t)B_SZ * D_DIM * 2);
  __hip_bfloat16* We1T = (__hip_bfloat16*)alloc((size_t)E_EXP * BOT0 * D_DIM * 2);
  __hip_bfloat16* We2T = (__hip_bfloat16*)alloc((size_t)E_EXP * BOT1 * BOT0 * 2);
  __hip_bfloat16* H    = (__hip_bfloat16*)alloc((size_t)E_EXP * B_SZ * BOT0 * 2);
  __hip_bfloat16* fea  = (__hip_bfloat16*)alloc((size_t)E_EXP * B_SZ * BOT1 * 2);
  float* gate = (float*)alloc((size_t)T_TASK * B_SZ * E_EXP * 4);
  __hip_bfloat16* WgT  = (__hip_bfloat16*)alloc((size_t)T_TASK * E_EXP * D_DIM * 2);

  // opt-in to 128 KiB dynamic LDS for the 8-phase GEMM (host-side, capture-safe)
  hipFuncSetAttribute((const void*)gemm8p,
                      hipFuncAttributeMaxDynamicSharedMemorySize, 131072);

  // 1. weight transpose/convert
  transpose_to_bf16<<<dim3(BOT0 / 32, D_DIM / 32, E_EXP), 256, 0, stream>>>(We1, We1T, D_DIM, BOT0);
  transpose_to_bf16<<<dim3(BOT1 / 32, BOT0 / 32, E_EXP), 256, 0, stream>>>(We2, We2T, BOT0, BOT1);
  wg_transpose<<<dim3(T_TASK * E_EXP * D_DIM / 256), 256, 0, stream>>>(Wg, WgT);

  // 2. embedding gather + numeric linear
  embed_convert<<<dim3(B_SZ / 4), 256, 0, stream>>>(cat, numx, offsets, W_emb, Wn, bnv, emb);

  // 3. gate GEMM + softmax
  gate_mfma<<<dim3(B_SZ / 64), 256, 0, stream>>>(emb, WgT, bg, gate);

  // 4. expert layer 1: (4096x1728)x(1728x512) x8 -> H   [grid 16x2x8 = 256 blocks = 1/CU]
  gemm8p<<<dim3(B_SZ / 256, BOT0 / 256, E_EXP), 512, 131072, stream>>>(
      emb, (size_t)0, We1T, be1, H, B_SZ, BOT0, D_DIM);

  // 5. expert layer 2: (4096x512)x(512x256) x8 -> fea   [grid 16x1x8 = 128 blocks]
  gemm8p<<<dim3(B_SZ / 256, BOT1 / 256, E_EXP), 512, 131072, stream>>>(
      H, (size_t)B_SZ * BOT0, We2T, be2, fea, B_SZ, BOT1, BOT0);

  // 6. gated combine + towers + sigmoid
  combine_tower<<<dim3(B_SZ / TB, T_TASK), 256, 0, stream>>>(
      gate, fea, Wt1, bt1, Wt2, bt2, Wt3, bt3, out);
}

// Round 5
// 134.774 us; speedup vs baseline: 2.5512x; 1.0387x over previous
//
#include <hip/hip_runtime.h>
#include <hip/hip_bf16.h>

#define B_SZ 4096
#define F_CAT 26
#define NUM_N 13
#define ED 64
#define D_DIM 1728   // 27*64
#define E_EXP 8
#define T_TASK 2
#define BOT0 512
#define BOT1 256
#define TOW0 128
#define TOW1 64

typedef __bf16 bf16x8 __attribute__((ext_vector_type(8)));
typedef float f32x4 __attribute__((ext_vector_type(4)));

__device__ __forceinline__ void gload_lds16(const void* g, void* l) {
  __builtin_amdgcn_global_load_lds(
      (const __attribute__((address_space(1))) void*)g,
      (__attribute__((address_space(3))) void*)l, 16, 0, 0);
}

#define BAR() do { asm volatile("" ::: "memory"); __builtin_amdgcn_s_barrier(); asm volatile("" ::: "memory"); } while (0)
#define LGKM0() do { asm volatile("s_waitcnt lgkmcnt(0)" ::: "memory"); __builtin_amdgcn_sched_barrier(0); } while (0)
#define VM8() asm volatile("s_waitcnt vmcnt(8)" ::: "memory")

// ---------------- fused weight prep: We1/We2 transpose->bf16 + Wg transpose
__device__ __forceinline__ void trans_tile(
    const float* __restrict__ inp, __hip_bfloat16* __restrict__ outp,
    int R, int C, int cx, int ry, float (*tile)[33])
{
  int c0 = cx * 32, r0 = ry * 32;
  int tx = threadIdx.x & 31, ty = threadIdx.x >> 5; // 32 x 8
#pragma unroll
  for (int i = 0; i < 32; i += 8)
    tile[ty + i][tx] = inp[(size_t)(r0 + ty + i) * C + c0 + tx];
  __syncthreads();
#pragma unroll
  for (int i = 0; i < 32; i += 8)
    outp[(size_t)(c0 + ty + i) * R + r0 + tx] = __float2bfloat16(tile[tx][ty + i]);
}

// We1 tiles: 16x54x8 = 6912 ; We2 tiles: 8x16x8 = 1024 ; Wg: 108 blocks
__global__ __launch_bounds__(256) void prep_weights(
    const float* __restrict__ We1, const float* __restrict__ We2,
    const float* __restrict__ Wg,
    __hip_bfloat16* __restrict__ We1T, __hip_bfloat16* __restrict__ We2T,
    __hip_bfloat16* __restrict__ WgT)
{
  __shared__ float tile[32][33];
  int id = blockIdx.x;
  if (id < 6912) {
    int z = id / 864, r = id - z * 864;
    int cx = r & 15, ry = r >> 4;
    trans_tile(We1 + (size_t)z * D_DIM * BOT0, We1T + (size_t)z * D_DIM * BOT0,
               D_DIM, BOT0, cx, ry, tile);
  } else if (id < 7936) {
    int r2 = id - 6912;
    int z = r2 >> 7, r = r2 & 127;
    int cx = r & 7, ry = r >> 3;
    trans_tile(We2 + (size_t)z * BOT0 * BOT1, We2T + (size_t)z * BOT0 * BOT1,
               BOT0, BOT1, cx, ry, tile);
  } else {
    int i = (id - 7936) * 256 + threadIdx.x; // over 16*1728
    int n = i / D_DIM, d = i - n * D_DIM;
    int t = n >> 3, e2 = n & 7;
    WgT[i] = __float2bfloat16(Wg[((size_t)t * D_DIM + d) * E_EXP + e2]);
  }
}

// ---------------- embedding gather + numeric linear -> emb bf16 (4 batch rows / block)
__global__ __launch_bounds__(256) void embed_convert(
    const int* __restrict__ cat, const float* __restrict__ numx,
    const int* __restrict__ offsets, const float* __restrict__ W_emb,
    const float* __restrict__ Wn, const float* __restrict__ bnum,
    __hip_bfloat16* __restrict__ emb)
{
  const int UNITS = 27 * 16; // float4 units per row
  int b0 = blockIdx.x * 4;
  for (int idx = threadIdx.x; idx < 4 * UNITS; idx += 256) {
    int r = idx / UNITS, u = idx - r * UNITS;
    int f = u >> 4, d4 = (u & 15) * 4;
    int b = b0 + r;
    float4 v;
    if (f < F_CAT) {
      int row = cat[(size_t)b * F_CAT + f] + offsets[f];
      v = *reinterpret_cast<const float4*>(&W_emb[(size_t)row * ED + d4]);
    } else {
      float a0 = bnum[d4], a1 = bnum[d4 + 1], a2 = bnum[d4 + 2], a3 = bnum[d4 + 3];
#pragma unroll
      for (int n = 0; n < NUM_N; ++n) {
        float x = numx[(size_t)b * NUM_N + n];
        const float* wr = &Wn[n * ED + d4];
        a0 = fmaf(x, wr[0], a0);
        a1 = fmaf(x, wr[1], a1);
        a2 = fmaf(x, wr[2], a2);
        a3 = fmaf(x, wr[3], a3);
      }
      v = make_float4(a0, a1, a2, a3);
    }
    union { __hip_bfloat16 h[4]; uint2 u2; } pk;
    pk.h[0] = __float2bfloat16(v.x);
    pk.h[1] = __float2bfloat16(v.y);
    pk.h[2] = __float2bfloat16(v.z);
    pk.h[3] = __float2bfloat16(v.w);
    *reinterpret_cast<uint2*>(&emb[(size_t)b * D_DIM + f * ED + d4]) = pk.u2;
  }
}

// ---------------- gate GEMM (M=4096, N=16, K=1728) via MFMA + fused per-task softmax
__global__ __launch_bounds__(256) void gate_mfma(
    const __hip_bfloat16* __restrict__ emb, const __hip_bfloat16* __restrict__ WgT,
    const float* __restrict__ bg, float* __restrict__ gate)
{
  int wid = threadIdx.x >> 6, lane = threadIdx.x & 63;
  int l15 = lane & 15, lh = lane >> 4;
  int r0 = (blockIdx.x * 4 + wid) * 16;
  f32x4 acc = {};
  const __hip_bfloat16* arow = emb + (size_t)(r0 + l15) * D_DIM + lh * 8;
  const __hip_bfloat16* brow = WgT + (size_t)l15 * D_DIM + lh * 8;
#pragma unroll 4
  for (int k = 0; k < D_DIM; k += 32) {
    bf16x8 af = *reinterpret_cast<const bf16x8*>(arow + k);
    bf16x8 bf = *reinterpret_cast<const bf16x8*>(brow + k);
    acc = __builtin_amdgcn_mfma_f32_16x16x32_bf16(af, bf, acc, 0, 0, 0);
  }
  int t = l15 >> 3, e = l15 & 7;
  float bv = bg[t * E_EXP + e];
#pragma unroll
  for (int r = 0; r < 4; ++r) {
    float lg = acc[r] + bv;
    float m = lg;
    m = fmaxf(m, __shfl_xor(m, 1));
    m = fmaxf(m, __shfl_xor(m, 2));
    m = fmaxf(m, __shfl_xor(m, 4));
    float ex = expf(lg - m);
    float s = ex;
    s += __shfl_xor(s, 1);
    s += __shfl_xor(s, 2);
    s += __shfl_xor(s, 4);
    int row = r0 + lh * 4 + r;
    gate[((size_t)t * B_SZ + row) * E_EXP + e] = ex / s;
  }
}

// =========================================================================
// 8-phase 256x256 BK=64 bf16 MFMA GEMM. 8 waves (2M x 4N), per-wave C=128x64.
// st_16x32 LDS swizzle (both sides). This round: all LDS/global addresses
// hoisted out of the K-loop (pointer-bump staging, imm-offset ds_reads) and
// the single vmcnt(4) split into two vmcnt(8) waits (p1 certifies cur-k1,
// p3 certifies next-k0) so every certified load is >=4 phases old.
// LDS: A slabs (buf*2+s)*16384 at 0; B same at +65536. 128 KiB total.
// =========================================================================
__device__ __forceinline__ void mfma16(const bf16x8* a, const bf16x8* b, f32x4 (*accRows)[4]) {
#pragma unroll
  for (int i = 0; i < 4; ++i)
#pragma unroll
    for (int j = 0; j < 4; ++j)
      accRows[i][j] = __builtin_amdgcn_mfma_f32_16x16x32_bf16(a[i], b[j], accRows[i][j], 0, 0, 0);
}

__global__ __launch_bounds__(512, 2) void gemm8p(
    const __hip_bfloat16* __restrict__ A, size_t strideAe,
    const __hip_bfloat16* __restrict__ BT,
    const float* __restrict__ bias,
    __hip_bfloat16* __restrict__ C,
    int M, int N, int K)
{
  extern __shared__ char smem[];
  int e = blockIdx.z;
  const __hip_bfloat16* Ap = A + strideAe * (size_t)e;
  const __hip_bfloat16* Bp = BT + (size_t)e * N * K;
  const float* bp = bias + (size_t)e * N;
  __hip_bfloat16* Cp = C + (size_t)e * M * N;
  int bm0 = blockIdx.x * 256, bn0 = blockIdx.y * 256;

  int tid = threadIdx.x;
  int wid = tid >> 6, lane = tid & 63;
  int l15 = lane & 15, lh = lane >> 4;
  int wrow = (wid >> 2) * 128, wcol = (wid & 3) * 64;

  // hoisted LDS read bases (st_16x32: slot = lh ^ ((l15>>3)<<1), const/thread)
  int slotc = (lh ^ (((l15 >> 3) & 1) << 1)) << 4;
  const char* rdA = smem + (wrow + l15) * 64 + slotc;
  const char* rdB = smem + 65536 + (wcol + l15) * 64 + slotc;
  // hoisted LDS staging dest bases (wave-uniform; HW adds lane*16)
  char* stA = smem + (wid << 10);
  char* stB = smem + 65536 + (wid << 10);

  // hoisted global staging pointers (advance +64 elem = 128 B per tile)
  const __hip_bfloat16* gA[2];
  const __hip_bfloat16* gB[2];
#pragma unroll
  for (int j = 0; j < 2; ++j) {
    int X = (wid << 10) + (lane << 4) + (j << 13);
    int row = X >> 6;
    int ss = ((X >> 4) & 3) ^ (((row >> 3) & 1) << 1);
    gA[j] = Ap + (size_t)(bm0 + row) * K + ss * 8;
    gB[j] = Bp + (size_t)(bn0 + row) * K + ss * 8;
  }

  f32x4 acc[8][4] = {};
  int NT = K >> 6;

  // ---- prologue: T0-k0, T0-k1, T1-k0 (12 gload instr); vmcnt(8) certifies T0-k0
#pragma unroll
  for (int j = 0; j < 2; ++j) gload_lds16(gA[j], stA + (j << 13));
#pragma unroll
  for (int j = 0; j < 2; ++j) gload_lds16(gB[j], stB + (j << 13));
#pragma unroll
  for (int j = 0; j < 2; ++j) gload_lds16(gA[j] + 32, stA + 16384 + (j << 13));
#pragma unroll
  for (int j = 0; j < 2; ++j) gload_lds16(gB[j] + 32, stB + 16384 + (j << 13));
#pragma unroll
  for (int j = 0; j < 2; ++j) gload_lds16(gA[j] + 64, stA + 32768 + (j << 13));
#pragma unroll
  for (int j = 0; j < 2; ++j) gload_lds16(gB[j] + 64, stB + 32768 + (j << 13));
  VM8();
  BAR();

  for (int T = 0; T < NT; ++T) {
    int par = (T & 1) << 15;   // cur buffer byte offset
    int qar = par ^ 32768;     // next buffer
    const char* As = rdA + par;
    const char* Bs = rdB + par;
    bf16x8 a[4], b[4];

    // ---- p0: k0, rows wrow..+63; stage A-k1(T+1) -> slab(q,1)
#pragma unroll
    for (int i = 0; i < 4; ++i) a[i] = *(const bf16x8*)(As + i * 1024);
#pragma unroll
    for (int j = 0; j < 4; ++j) b[j] = *(const bf16x8*)(Bs + j * 1024);
#pragma unroll
    for (int j = 0; j < 2; ++j) gload_lds16(gA[j] + 96, stA + qar + 16384 + (j << 13));
    BAR(); LGKM0();
    __builtin_amdgcn_s_setprio(1); mfma16(a, b, acc); __builtin_amdgcn_s_setprio(0);
    BAR();

    // ---- p1: k0, rows +64..127; stage B-k1(T+1); vmcnt(8) certifies cur-k1
#pragma unroll
    for (int i = 0; i < 4; ++i) a[i] = *(const bf16x8*)(As + 4096 + i * 1024);
#pragma unroll
    for (int j = 0; j < 2; ++j) gload_lds16(gB[j] + 96, stB + qar + 16384 + (j << 13));
    BAR(); LGKM0();
    __builtin_amdgcn_s_setprio(1); mfma16(a, b, acc + 4); __builtin_amdgcn_s_setprio(0);
    VM8();
    BAR();

    // ---- p2: k1, rows wrow..+63; stage A-k0(T+2) -> slab(p,0)
#pragma unroll
    for (int i = 0; i < 4; ++i) a[i] = *(const bf16x8*)(As + 16384 + i * 1024);
#pragma unroll
    for (int j = 0; j < 4; ++j) b[j] = *(const bf16x8*)(Bs + 16384 + j * 1024);
#pragma unroll
    for (int j = 0; j < 2; ++j) gload_lds16(gA[j] + 128, stA + par + (j << 13));
    BAR(); LGKM0();
    __builtin_amdgcn_s_setprio(1); mfma16(a, b, acc); __builtin_amdgcn_s_setprio(0);
    BAR();

    // ---- p3: k1, rows +64..127; stage B-k0(T+2); vmcnt(8) certifies next-k0
#pragma unroll
    for (int i = 0; i < 4; ++i) a[i] = *(const bf16x8*)(As + 16384 + 4096 + i * 1024);
#pragma unroll
    for (int j = 0; j < 2; ++j) gload_lds16(gB[j] + 128, stB + par + (j << 13));
    BAR(); LGKM0();
    __builtin_amdgcn_s_setprio(1); mfma16(a, b, acc + 4); __builtin_amdgcn_s_setprio(0);
    VM8();
    BAR();

#pragma unroll
    for (int j = 0; j < 2; ++j) { gA[j] += 64; gB[j] += 64; }
  }

  // ---- epilogue: drain tail prefetches (they land in LDS!), then stage C
  // through LDS as bf16 [256][256] and store fully coalesced (16 B/lane).
  asm volatile("s_waitcnt vmcnt(0)" ::: "memory");
  BAR();
  __hip_bfloat16* cs = (__hip_bfloat16*)smem;
#pragma unroll
  for (int nj = 0; nj < 4; ++nj) {
    int col = wcol + nj * 16 + l15;
    float bv = bp[bn0 + col];
#pragma unroll
    for (int mi = 0; mi < 8; ++mi) {
      int rb = wrow + mi * 16 + lh * 4;
#pragma unroll
      for (int r = 0; r < 4; ++r) {
        float v = acc[mi][nj][r] + bv;
        cs[(size_t)(rb + r) * 256 + col] = __float2bfloat16(fmaxf(v, 0.f));
      }
    }
  }
  BAR();
  {
    int rr = tid >> 5, c8 = (tid & 31) * 8; // 16 rows/pass, 32 x 16B per row
#pragma unroll
    for (int p = 0; p < 16; ++p) {
      int row = p * 16 + rr;
      *reinterpret_cast<uint4*>(&Cp[(size_t)(bm0 + row) * N + bn0 + c8]) =
          *reinterpret_cast<const uint4*>(&cs[(size_t)row * 256 + c8]);
    }
  }
}

// ---------------- gate-combine + tower MLPs + sigmoid (16 batch rows per block)
#define TB 16
__global__ __launch_bounds__(256) void combine_tower(
    const float* __restrict__ gate, const __hip_bfloat16* __restrict__ fea,
    const float* __restrict__ Wt1, const float* __restrict__ bt1,
    const float* __restrict__ Wt2, const float* __restrict__ bt2,
    const float* __restrict__ Wt3, const float* __restrict__ bt3,
    float* __restrict__ out)
{
  int t = blockIdx.y;
  int b0 = blockIdx.x * TB;
  int tid = threadIdx.x;
  __shared__ float gs[TB][E_EXP];
  __shared__ float tf[TB][BOT1];
  __shared__ float h1[TB][TOW0];
  __shared__ float h2[TB][TOW1];
  if (tid < TB * E_EXP) {
    int bl = tid >> 3, e = tid & 7;
    gs[bl][e] = gate[((size_t)t * B_SZ + b0 + bl) * E_EXP + e];
  }
  __syncthreads();
  // task_fea = sum_e gate * fea
  for (int i = tid; i < TB * BOT1; i += 256) {
    int bl = i >> 8, o = i & 255;
    float s = 0.f;
#pragma unroll
    for (int e = 0; e < E_EXP; ++e)
      s = fmaf(gs[bl][e], __bfloat162float(fea[((size_t)e * B_SZ + b0 + bl) * BOT1 + o]), s);
    tf[bl][o] = s;
  }
  __syncthreads();
  // tower layer 1: 256 -> 128
  {
    int h = tid & 127, half = tid >> 7;
    float a[8] = {0, 0, 0, 0, 0, 0, 0, 0};
    for (int d = 0; d < BOT1; ++d) {
      float w = Wt1[((size_t)t * BOT1 + d) * TOW0 + h];
#pragma unroll
      for (int q = 0; q < 8; ++q) a[q] = fmaf(w, tf[half * 8 + q][d], a[q]);
    }
    float bv = bt1[t * TOW0 + h];
#pragma unroll
    for (int q = 0; q < 8; ++q) h1[half * 8 + q][h] = fmaxf(a[q] + bv, 0.f);
  }
  __syncthreads();
  // tower layer 2: 128 -> 64
  {
    int h = tid & 63, qt = tid >> 6;
    float a[4] = {0, 0, 0, 0};
    for (int d = 0; d < TOW0; ++d) {
      float w = Wt2[((size_t)t * TOW0 + d) * TOW1 + h];
#pragma unroll
      for (int q = 0; q < 4; ++q) a[q] = fmaf(w, h1[qt * 4 + q][d], a[q]);
    }
    float bv = bt2[t * TOW1 + h];
#pragma unroll
    for (int q = 0; q < 4; ++q) h2[qt * 4 + q][h] = fmaxf(a[q] + bv, 0.f);
  }
  __syncthreads();
  // tower layer 3: 64 -> 1 + sigmoid
  {
    int l16 = tid & 15, bl = tid >> 4;
    float p = 0.f;
#pragma unroll
    for (int d = l16; d < TOW1; d += 16) p = fmaf(h2[bl][d], Wt3[t * TOW1 + d], p);
#pragma unroll
    for (int o = 8; o; o >>= 1) p += __shfl_down(p, o, 16);
    if (l16 == 0) {
      float lg = p + bt3[t];
      out[(size_t)t * B_SZ + b0 + bl] = 1.f / (1.f + expf(-lg));
    }
  }
}

extern "C" void kernel_launch(void* const* d_in, const int* in_sizes, int n_in,
                              void* d_out, int out_size, void* d_ws, size_t ws_size,
                              hipStream_t stream) {
  const int* cat = (const int*)d_in[0];
  const float* numx = (const float*)d_in[1];
  const int* offsets = (const int*)d_in[2];
  const float* W_emb = (const float*)d_in[3];
  const float* Wn = (const float*)d_in[4];
  const float* bnv = (const float*)d_in[5];
  const float* We1 = (const float*)d_in[6];
  const float* be1 = (const float*)d_in[7];
  const float* We2 = (const float*)d_in[8];
  const float* be2 = (const float*)d_in[9];
  const float* Wg = (const float*)d_in[10];
  const float* bg = (const float*)d_in[11];
  const float* Wt1 = (const float*)d_in[12];
  const float* bt1 = (const float*)d_in[13];
  const float* Wt2 = (const float*)d_in[14];
  const float* bt2 = (const float*)d_in[15];
  const float* Wt3 = (const float*)d_in[16];
  const float* bt3 = (const float*)d_in[17];
  float* out = (float*)d_out;

  char* ws = (char*)d_ws;
  size_t off = 0;
  auto alloc = [&](size_t bytes) {
    char* p = ws + off;
    off += (bytes + 255) & ~(size_t)255;
    return p;
  };
  __hip_bfloat16* emb  = (__hip_bfloat16*)alloc((size_t)B_SZ * D_DIM * 2);
  __hip_bfloat16* We1T = (__hip_bfloat16*)alloc((size_t)E_EXP * BOT0 * D_DIM * 2);
  __hip_bfloat16* We2T = (__hip_bfloat16*)alloc((size_t)E_EXP * BOT1 * BOT0 * 2);
  __hip_bfloat16* H    = (__hip_bfloat16*)alloc((size_t)E_EXP * B_SZ * BOT0 * 2);
  __hip_bfloat16* fea  = (__hip_bfloat16*)alloc((size_t)E_EXP * B_SZ * BOT1 * 2);
  float* gate = (float*)alloc((size_t)T_TASK * B_SZ * E_EXP * 4);
  __hip_bfloat16* WgT  = (__hip_bfloat16*)alloc((size_t)T_TASK * E_EXP * D_DIM * 2);
  (void)alloc(4096); // slack: gemm8p tail prefetch reads overrun up to ~256 B

  // opt-in to 128 KiB dynamic LDS for the 8-phase GEMM (host-side, capture-safe)
  hipFuncSetAttribute((const void*)gemm8p,
                      hipFuncAttributeMaxDynamicSharedMemorySize, 131072);

  // 1. fused weight prep (We1T, We2T, WgT)
  prep_weights<<<dim3(8044), 256, 0, stream>>>(We1, We2, Wg, We1T, We2T, WgT);

  // 2. embedding gather + numeric linear
  embed_convert<<<dim3(B_SZ / 4), 256, 0, stream>>>(cat, numx, offsets, W_emb, Wn, bnv, emb);

  // 3. gate GEMM + softmax
  gate_mfma<<<dim3(B_SZ / 64), 256, 0, stream>>>(emb, WgT, bg, gate);

  // 4. expert layer 1: (4096x1728)x(1728x512) x8 -> H   [grid 16x2x8 = 256 blocks = 1/CU]
  gemm8p<<<dim3(B_SZ / 256, BOT0 / 256, E_EXP), 512, 131072, stream>>>(
      emb, (size_t)0, We1T, be1, H, B_SZ, BOT0, D_DIM);

  // 5. expert layer 2: (4096x512)x(512x256) x8 -> fea   [grid 16x1x8 = 128 blocks]
  gemm8p<<<dim3(B_SZ / 256, BOT1 / 256, E_EXP), 512, 131072, stream>>>(
      H, (size_t)B_SZ * BOT0, We2T, be2, fea, B_SZ, BOT1, BOT0);

  // 6. gated combine + towers + sigmoid
  combine_tower<<<dim3(B_SZ / TB, T_TASK), 256, 0, stream>>>(
      gate, fea, Wt1, bt1, Wt2, bt2, Wt3, bt3, out);
}

// Round 6
// 131.457 us; speedup vs baseline: 2.6155x; 1.0252x over previous
//
#include <hip/hip_runtime.h>
#include <hip/hip_bf16.h>

#define B_SZ 4096
#define F_CAT 26
#define NUM_N 13
#define ED 64
#define D_DIM 1728   // 27*64
#define E_EXP 8
#define T_TASK 2
#define BOT0 512
#define BOT1 256
#define TOW0 128
#define TOW1 64

typedef __bf16 bf16x8 __attribute__((ext_vector_type(8)));
typedef float f32x4 __attribute__((ext_vector_type(4)));

__device__ __forceinline__ void gload_lds16(const void* g, void* l) {
  __builtin_amdgcn_global_load_lds(
      (const __attribute__((address_space(1))) void*)g,
      (__attribute__((address_space(3))) void*)l, 16, 0, 0);
}

#define BAR() do { asm volatile("" ::: "memory"); __builtin_amdgcn_s_barrier(); asm volatile("" ::: "memory"); } while (0)
#define VM8() asm volatile("s_waitcnt vmcnt(8)" ::: "memory")
#define VM6() asm volatile("s_waitcnt vmcnt(6)" ::: "memory")

// ---------------- fused weight prep: We1/We2 transpose->bf16 + Wg transpose
__device__ __forceinline__ void trans_tile(
    const float* __restrict__ inp, __hip_bfloat16* __restrict__ outp,
    int R, int C, int cx, int ry, float (*tile)[33])
{
  int c0 = cx * 32, r0 = ry * 32;
  int tx = threadIdx.x & 31, ty = threadIdx.x >> 5; // 32 x 8
#pragma unroll
  for (int i = 0; i < 32; i += 8)
    tile[ty + i][tx] = inp[(size_t)(r0 + ty + i) * C + c0 + tx];
  __syncthreads();
#pragma unroll
  for (int i = 0; i < 32; i += 8)
    outp[(size_t)(c0 + ty + i) * R + r0 + tx] = __float2bfloat16(tile[tx][ty + i]);
}

// We1 tiles: 16x54x8 = 6912 ; We2 tiles: 8x16x8 = 1024 ; Wg: 108 blocks
__global__ __launch_bounds__(256) void prep_weights(
    const float* __restrict__ We1, const float* __restrict__ We2,
    const float* __restrict__ Wg,
    __hip_bfloat16* __restrict__ We1T, __hip_bfloat16* __restrict__ We2T,
    __hip_bfloat16* __restrict__ WgT)
{
  __shared__ float tile[32][33];
  int id = blockIdx.x;
  if (id < 6912) {
    int z = id / 864, r = id - z * 864;
    int cx = r & 15, ry = r >> 4;
    trans_tile(We1 + (size_t)z * D_DIM * BOT0, We1T + (size_t)z * D_DIM * BOT0,
               D_DIM, BOT0, cx, ry, tile);
  } else if (id < 7936) {
    int r2 = id - 6912;
    int z = r2 >> 7, r = r2 & 127;
    int cx = r & 7, ry = r >> 3;
    trans_tile(We2 + (size_t)z * BOT0 * BOT1, We2T + (size_t)z * BOT0 * BOT1,
               BOT0, BOT1, cx, ry, tile);
  } else {
    int i = (id - 7936) * 256 + threadIdx.x; // over 16*1728
    int n = i / D_DIM, d = i - n * D_DIM;
    int t = n >> 3, e2 = n & 7;
    WgT[i] = __float2bfloat16(Wg[((size_t)t * D_DIM + d) * E_EXP + e2]);
  }
}

// ---------------- embedding gather + numeric linear -> emb bf16 (4 batch rows / block)
__global__ __launch_bounds__(256) void embed_convert(
    const int* __restrict__ cat, const float* __restrict__ numx,
    const int* __restrict__ offsets, const float* __restrict__ W_emb,
    const float* __restrict__ Wn, const float* __restrict__ bnum,
    __hip_bfloat16* __restrict__ emb)
{
  const int UNITS = 27 * 16; // float4 units per row
  int b0 = blockIdx.x * 4;
  for (int idx = threadIdx.x; idx < 4 * UNITS; idx += 256) {
    int r = idx / UNITS, u = idx - r * UNITS;
    int f = u >> 4, d4 = (u & 15) * 4;
    int b = b0 + r;
    float4 v;
    if (f < F_CAT) {
      int row = cat[(size_t)b * F_CAT + f] + offsets[f];
      v = *reinterpret_cast<const float4*>(&W_emb[(size_t)row * ED + d4]);
    } else {
      float a0 = bnum[d4], a1 = bnum[d4 + 1], a2 = bnum[d4 + 2], a3 = bnum[d4 + 3];
#pragma unroll
      for (int n = 0; n < NUM_N; ++n) {
        float x = numx[(size_t)b * NUM_N + n];
        const float* wr = &Wn[n * ED + d4];
        a0 = fmaf(x, wr[0], a0);
        a1 = fmaf(x, wr[1], a1);
        a2 = fmaf(x, wr[2], a2);
        a3 = fmaf(x, wr[3], a3);
      }
      v = make_float4(a0, a1, a2, a3);
    }
    union { __hip_bfloat16 h[4]; uint2 u2; } pk;
    pk.h[0] = __float2bfloat16(v.x);
    pk.h[1] = __float2bfloat16(v.y);
    pk.h[2] = __float2bfloat16(v.z);
    pk.h[3] = __float2bfloat16(v.w);
    *reinterpret_cast<uint2*>(&emb[(size_t)b * D_DIM + f * ED + d4]) = pk.u2;
  }
}

// ---------------- gate GEMM (M=4096, N=16, K=1728) via MFMA + fused per-task softmax
__global__ __launch_bounds__(256) void gate_mfma(
    const __hip_bfloat16* __restrict__ emb, const __hip_bfloat16* __restrict__ WgT,
    const float* __restrict__ bg, float* __restrict__ gate)
{
  int wid = threadIdx.x >> 6, lane = threadIdx.x & 63;
  int l15 = lane & 15, lh = lane >> 4;
  int r0 = (blockIdx.x * 4 + wid) * 16;
  f32x4 acc = {};
  const __hip_bfloat16* arow = emb + (size_t)(r0 + l15) * D_DIM + lh * 8;
  const __hip_bfloat16* brow = WgT + (size_t)l15 * D_DIM + lh * 8;
#pragma unroll 4
  for (int k = 0; k < D_DIM; k += 32) {
    bf16x8 af = *reinterpret_cast<const bf16x8*>(arow + k);
    bf16x8 bf = *reinterpret_cast<const bf16x8*>(brow + k);
    acc = __builtin_amdgcn_mfma_f32_16x16x32_bf16(af, bf, acc, 0, 0, 0);
  }
  int t = l15 >> 3, e = l15 & 7;
  float bv = bg[t * E_EXP + e];
#pragma unroll
  for (int r = 0; r < 4; ++r) {
    float lg = acc[r] + bv;
    float m = lg;
    m = fmaxf(m, __shfl_xor(m, 1));
    m = fmaxf(m, __shfl_xor(m, 2));
    m = fmaxf(m, __shfl_xor(m, 4));
    float ex = expf(lg - m);
    float s = ex;
    s += __shfl_xor(s, 1);
    s += __shfl_xor(s, 2);
    s += __shfl_xor(s, 4);
    int row = r0 + lh * 4 + r;
    gate[((size_t)t * B_SZ + row) * E_EXP + e] = ex / s;
  }
}

__device__ __forceinline__ void mfma16(const bf16x8* a, const bf16x8* b, f32x4 (*accRows)[4]) {
#pragma unroll
  for (int i = 0; i < 4; ++i)
#pragma unroll
    for (int j = 0; j < 4; ++j)
      accRows[i][j] = __builtin_amdgcn_mfma_f32_16x16x32_bf16(a[i], b[j], accRows[i][j], 0, 0, 0);
}

// =========================================================================
// 8-phase 256x256 BK=64 GEMM. This round: LGKM0 (full lgkmcnt(0) drain +
// sched_barrier(0)) REMOVED — compiler emits fine-grained per-operand
// lgkmcnt, letting each wave enter MFMA while other waves' LDS reads drain
// (m97/m141 evidence). Barriers + counted vmcnt(8) unchanged.
// =========================================================================
__global__ __launch_bounds__(512, 2) void gemm8p(
    const __hip_bfloat16* __restrict__ A, size_t strideAe,
    const __hip_bfloat16* __restrict__ BT,
    const float* __restrict__ bias,
    __hip_bfloat16* __restrict__ C,
    int M, int N, int K)
{
  extern __shared__ char smem[];
  int e = blockIdx.z;
  const __hip_bfloat16* Ap = A + strideAe * (size_t)e;
  const __hip_bfloat16* Bp = BT + (size_t)e * N * K;
  const float* bp = bias + (size_t)e * N;
  __hip_bfloat16* Cp = C + (size_t)e * M * N;
  int bm0 = blockIdx.x * 256, bn0 = blockIdx.y * 256;

  int tid = threadIdx.x;
  int wid = tid >> 6, lane = tid & 63;
  int l15 = lane & 15, lh = lane >> 4;
  int wrow = (wid >> 2) * 128, wcol = (wid & 3) * 64;

  int slotc = (lh ^ (((l15 >> 3) & 1) << 1)) << 4;
  const char* rdA = smem + (wrow + l15) * 64 + slotc;
  const char* rdB = smem + 65536 + (wcol + l15) * 64 + slotc;
  char* stA = smem + (wid << 10);
  char* stB = smem + 65536 + (wid << 10);

  const __hip_bfloat16* gA[2];
  const __hip_bfloat16* gB[2];
#pragma unroll
  for (int j = 0; j < 2; ++j) {
    int X = (wid << 10) + (lane << 4) + (j << 13);
    int row = X >> 6;
    int ss = ((X >> 4) & 3) ^ (((row >> 3) & 1) << 1);
    gA[j] = Ap + (size_t)(bm0 + row) * K + ss * 8;
    gB[j] = Bp + (size_t)(bn0 + row) * K + ss * 8;
  }

  f32x4 acc[8][4] = {};
  int NT = K >> 6;

#pragma unroll
  for (int j = 0; j < 2; ++j) gload_lds16(gA[j], stA + (j << 13));
#pragma unroll
  for (int j = 0; j < 2; ++j) gload_lds16(gB[j], stB + (j << 13));
#pragma unroll
  for (int j = 0; j < 2; ++j) gload_lds16(gA[j] + 32, stA + 16384 + (j << 13));
#pragma unroll
  for (int j = 0; j < 2; ++j) gload_lds16(gB[j] + 32, stB + 16384 + (j << 13));
#pragma unroll
  for (int j = 0; j < 2; ++j) gload_lds16(gA[j] + 64, stA + 32768 + (j << 13));
#pragma unroll
  for (int j = 0; j < 2; ++j) gload_lds16(gB[j] + 64, stB + 32768 + (j << 13));
  VM8();
  BAR();

  for (int T = 0; T < NT; ++T) {
    int par = (T & 1) << 15;
    int qar = par ^ 32768;
    const char* As = rdA + par;
    const char* Bs = rdB + par;
    bf16x8 a[4], b[4];

    // p0: k0, rows wrow..+63; stage A-k1(T+1)
#pragma unroll
    for (int i = 0; i < 4; ++i) a[i] = *(const bf16x8*)(As + i * 1024);
#pragma unroll
    for (int j = 0; j < 4; ++j) b[j] = *(const bf16x8*)(Bs + j * 1024);
#pragma unroll
    for (int j = 0; j < 2; ++j) gload_lds16(gA[j] + 96, stA + qar + 16384 + (j << 13));
    BAR();
    __builtin_amdgcn_s_setprio(1); mfma16(a, b, acc); __builtin_amdgcn_s_setprio(0);
    BAR();

    // p1: k0, rows +64..127; stage B-k1(T+1); vmcnt(8) certifies cur-k1
#pragma unroll
    for (int i = 0; i < 4; ++i) a[i] = *(const bf16x8*)(As + 4096 + i * 1024);
#pragma unroll
    for (int j = 0; j < 2; ++j) gload_lds16(gB[j] + 96, stB + qar + 16384 + (j << 13));
    BAR();
    __builtin_amdgcn_s_setprio(1); mfma16(a, b, acc + 4); __builtin_amdgcn_s_setprio(0);
    VM8();
    BAR();

    // p2: k1, rows wrow..+63; stage A-k0(T+2)
#pragma unroll
    for (int i = 0; i < 4; ++i) a[i] = *(const bf16x8*)(As + 16384 + i * 1024);
#pragma unroll
    for (int j = 0; j < 4; ++j) b[j] = *(const bf16x8*)(Bs + 16384 + j * 1024);
#pragma unroll
    for (int j = 0; j < 2; ++j) gload_lds16(gA[j] + 128, stA + par + (j << 13));
    BAR();
    __builtin_amdgcn_s_setprio(1); mfma16(a, b, acc); __builtin_amdgcn_s_setprio(0);
    BAR();

    // p3: k1, rows +64..127; stage B-k0(T+2); vmcnt(8) certifies next-k0
#pragma unroll
    for (int i = 0; i < 4; ++i) a[i] = *(const bf16x8*)(As + 16384 + 4096 + i * 1024);
#pragma unroll
    for (int j = 0; j < 2; ++j) gload_lds16(gB[j] + 128, stB + par + (j << 13));
    BAR();
    __builtin_amdgcn_s_setprio(1); mfma16(a, b, acc + 4); __builtin_amdgcn_s_setprio(0);
    VM8();
    BAR();

#pragma unroll
    for (int j = 0; j < 2; ++j) { gA[j] += 64; gB[j] += 64; }
  }

  asm volatile("s_waitcnt vmcnt(0)" ::: "memory");
  BAR();
  __hip_bfloat16* cs = (__hip_bfloat16*)smem;
#pragma unroll
  for (int nj = 0; nj < 4; ++nj) {
    int col = wcol + nj * 16 + l15;
    float bv = bp[bn0 + col];
#pragma unroll
    for (int mi = 0; mi < 8; ++mi) {
      int rb = wrow + mi * 16 + lh * 4;
#pragma unroll
      for (int r = 0; r < 4; ++r) {
        float v = acc[mi][nj][r] + bv;
        cs[(size_t)(rb + r) * 256 + col] = __float2bfloat16(fmaxf(v, 0.f));
      }
    }
  }
  BAR();
  {
    int rr = tid >> 5, c8 = (tid & 31) * 8;
#pragma unroll
    for (int p = 0; p < 16; ++p) {
      int row = p * 16 + rr;
      *reinterpret_cast<uint4*>(&Cp[(size_t)(bm0 + row) * N + bn0 + c8]) =
          *reinterpret_cast<const uint4*>(&cs[(size_t)row * 256 + c8]);
    }
  }
}

// =========================================================================
// BM=128 variant (gemm4p): 128x256 tile, 2 phases/K-tile, 8 waves 2Mx4N,
// per-wave C=64x64 (acc[4][4]). Fills 256 CUs for the N=256 GEMM2 shape.
// vmcnt(6) cadence: p0 stages (T+1)k1 [3 loads], p1 stages (T+2)k0 [3] —
// each VM6 leaves exactly the 6 newest outstanding, certifying slabs
// issued >=2 phases earlier. LDS: A 4x8KB @0, B 4x16KB @32768 (96 KB).
// =========================================================================
__global__ __launch_bounds__(512, 2) void gemm4p(
    const __hip_bfloat16* __restrict__ A, size_t strideAe,
    const __hip_bfloat16* __restrict__ BT,
    const float* __restrict__ bias,
    __hip_bfloat16* __restrict__ C,
    int M, int N, int K)
{
  extern __shared__ char smem[];
  int e = blockIdx.z;
  const __hip_bfloat16* Ap = A + strideAe * (size_t)e;
  const __hip_bfloat16* Bp = BT + (size_t)e * N * K;
  const float* bp = bias + (size_t)e * N;
  __hip_bfloat16* Cp = C + (size_t)e * M * N;
  int bm0 = blockIdx.x * 128, bn0 = blockIdx.y * 256;

  int tid = threadIdx.x;
  int wid = tid >> 6, lane = tid & 63;
  int l15 = lane & 15, lh = lane >> 4;
  int wrow = (wid >> 2) * 64, wcol = (wid & 3) * 64;

  int slotc = (lh ^ (((l15 >> 3) & 1) << 1)) << 4;
  const char* rdA = smem + (wrow + l15) * 64 + slotc;
  const char* rdB = smem + 32768 + (wcol + l15) * 64 + slotc;
  char* stA = smem + (wid << 10);
  char* stB = smem + 32768 + (wid << 10);

  const __hip_bfloat16* gA;
  const __hip_bfloat16* gB[2];
  {
    int X = (wid << 10) + (lane << 4);
    int row = X >> 6;
    int ss = ((X >> 4) & 3) ^ (((row >> 3) & 1) << 1);
    gA = Ap + (size_t)(bm0 + row) * K + ss * 8;
#pragma unroll
    for (int j = 0; j < 2; ++j) {
      int X2 = X + (j << 13);
      int row2 = X2 >> 6;
      int ss2 = ((X2 >> 4) & 3) ^ (((row2 >> 3) & 1) << 1);
      gB[j] = Bp + (size_t)(bn0 + row2) * K + ss2 * 8;
    }
  }

  f32x4 acc[4][4] = {};
  int NT = K >> 6;

  // prologue: T0k0(3), T0k1(3), T1k0(3); VM6 certifies T0k0
  gload_lds16(gA, stA);
#pragma unroll
  for (int j = 0; j < 2; ++j) gload_lds16(gB[j], stB + (j << 13));
  gload_lds16(gA + 32, stA + 8192);
#pragma unroll
  for (int j = 0; j < 2; ++j) gload_lds16(gB[j] + 32, stB + 16384 + (j << 13));
  gload_lds16(gA + 64, stA + 16384);
#pragma unroll
  for (int j = 0; j < 2; ++j) gload_lds16(gB[j] + 64, stB + 32768 + (j << 13));
  VM6();
  BAR();

  for (int T = 0; T < NT; ++T) {
    int pA = (T & 1) << 14, qA = pA ^ 16384;   // A buffer byte offsets
    int pB = (T & 1) << 15, qB = pB ^ 32768;   // B buffer byte offsets
    const char* As = rdA + pA;
    const char* Bs = rdB + pB;
    bf16x8 a[4], b[4];

    // p0: k0; stage (T+1)k1 [A:1, B:2]
#pragma unroll
    for (int i = 0; i < 4; ++i) a[i] = *(const bf16x8*)(As + i * 1024);
#pragma unroll
    for (int j = 0; j < 4; ++j) b[j] = *(const bf16x8*)(Bs + j * 1024);
    gload_lds16(gA + 96, stA + qA + 8192);
#pragma unroll
    for (int j = 0; j < 2; ++j) gload_lds16(gB[j] + 96, stB + qB + 16384 + (j << 13));
    BAR();
    __builtin_amdgcn_s_setprio(1); mfma16(a, b, acc); __builtin_amdgcn_s_setprio(0);
    VM6();
    BAR();

    // p1: k1; stage (T+2)k0 [A:1, B:2]
#pragma unroll
    for (int i = 0; i < 4; ++i) a[i] = *(const bf16x8*)(As + 8192 + i * 1024);
#pragma unroll
    for (int j = 0; j < 4; ++j) b[j] = *(const bf16x8*)(Bs + 16384 + j * 1024);
    gload_lds16(gA + 128, stA + pA);
#pragma unroll
    for (int j = 0; j < 2; ++j) gload_lds16(gB[j] + 128, stB + pB + (j << 13));
    BAR();
    __builtin_amdgcn_s_setprio(1); mfma16(a, b, acc); __builtin_amdgcn_s_setprio(0);
    VM6();
    BAR();

    gA += 64;
#pragma unroll
    for (int j = 0; j < 2; ++j) gB[j] += 64;
  }

  asm volatile("s_waitcnt vmcnt(0)" ::: "memory");
  BAR();
  __hip_bfloat16* cs = (__hip_bfloat16*)smem;
#pragma unroll
  for (int nj = 0; nj < 4; ++nj) {
    int col = wcol + nj * 16 + l15;
    float bv = bp[bn0 + col];
#pragma unroll
    for (int mi = 0; mi < 4; ++mi) {
      int rb = wrow + mi * 16 + lh * 4;
#pragma unroll
      for (int r = 0; r < 4; ++r) {
        float v = acc[mi][nj][r] + bv;
        cs[(size_t)(rb + r) * 256 + col] = __float2bfloat16(fmaxf(v, 0.f));
      }
    }
  }
  BAR();
  {
    int rr = tid >> 5, c8 = (tid & 31) * 8;
#pragma unroll
    for (int p = 0; p < 8; ++p) {
      int row = p * 16 + rr;
      *reinterpret_cast<uint4*>(&Cp[(size_t)(bm0 + row) * N + bn0 + c8]) =
          *reinterpret_cast<const uint4*>(&cs[(size_t)row * 256 + c8]);
    }
  }
}

// ---------------- gate-combine + tower MLPs + sigmoid (16 batch rows per block)
#define TB 16
__global__ __launch_bounds__(256) void combine_tower(
    const float* __restrict__ gate, const __hip_bfloat16* __restrict__ fea,
    const float* __restrict__ Wt1, const float* __restrict__ bt1,
    const float* __restrict__ Wt2, const float* __restrict__ bt2,
    const float* __restrict__ Wt3, const float* __restrict__ bt3,
    float* __restrict__ out)
{
  int t = blockIdx.y;
  int b0 = blockIdx.x * TB;
  int tid = threadIdx.x;
  __shared__ float gs[TB][E_EXP];
  __shared__ float tf[TB][BOT1];
  __shared__ float h1[TB][TOW0];
  __shared__ float h2[TB][TOW1];
  if (tid < TB * E_EXP) {
    int bl = tid >> 3, e = tid & 7;
    gs[bl][e] = gate[((size_t)t * B_SZ + b0 + bl) * E_EXP + e];
  }
  __syncthreads();
  for (int i = tid; i < TB * BOT1; i += 256) {
    int bl = i >> 8, o = i & 255;
    float s = 0.f;
#pragma unroll
    for (int e = 0; e < E_EXP; ++e)
      s = fmaf(gs[bl][e], __bfloat162float(fea[((size_t)e * B_SZ + b0 + bl) * BOT1 + o]), s);
    tf[bl][o] = s;
  }
  __syncthreads();
  {
    int h = tid & 127, half = tid >> 7;
    float a[8] = {0, 0, 0, 0, 0, 0, 0, 0};
    for (int d = 0; d < BOT1; ++d) {
      float w = Wt1[((size_t)t * BOT1 + d) * TOW0 + h];
#pragma unroll
      for (int q = 0; q < 8; ++q) a[q] = fmaf(w, tf[half * 8 + q][d], a[q]);
    }
    float bv = bt1[t * TOW0 + h];
#pragma unroll
    for (int q = 0; q < 8; ++q) h1[half * 8 + q][h] = fmaxf(a[q] + bv, 0.f);
  }
  __syncthreads();
  {
    int h = tid & 63, qt = tid >> 6;
    float a[4] = {0, 0, 0, 0};
    for (int d = 0; d < TOW0; ++d) {
      float w = Wt2[((size_t)t * TOW0 + d) * TOW1 + h];
#pragma unroll
      for (int q = 0; q < 4; ++q) a[q] = fmaf(w, h1[qt * 4 + q][d], a[q]);
    }
    float bv = bt2[t * TOW1 + h];
#pragma unroll
    for (int q = 0; q < 4; ++q) h2[qt * 4 + q][h] = fmaxf(a[q] + bv, 0.f);
  }
  __syncthreads();
  {
    int l16 = tid & 15, bl = tid >> 4;
    float p = 0.f;
#pragma unroll
    for (int d = l16; d < TOW1; d += 16) p = fmaf(h2[bl][d], Wt3[t * TOW1 + d], p);
#pragma unroll
    for (int o = 8; o; o >>= 1) p += __shfl_down(p, o, 16);
    if (l16 == 0) {
      float lg = p + bt3[t];
      out[(size_t)t * B_SZ + b0 + bl] = 1.f / (1.f + expf(-lg));
    }
  }
}

extern "C" void kernel_launch(void* const* d_in, const int* in_sizes, int n_in,
                              void* d_out, int out_size, void* d_ws, size_t ws_size,
                              hipStream_t stream) {
  const int* cat = (const int*)d_in[0];
  const float* numx = (const float*)d_in[1];
  const int* offsets = (const int*)d_in[2];
  const float* W_emb = (const float*)d_in[3];
  const float* Wn = (const float*)d_in[4];
  const float* bnv = (const float*)d_in[5];
  const float* We1 = (const float*)d_in[6];
  const float* be1 = (const float*)d_in[7];
  const float* We2 = (const float*)d_in[8];
  const float* be2 = (const float*)d_in[9];
  const float* Wg = (const float*)d_in[10];
  const float* bg = (const float*)d_in[11];
  const float* Wt1 = (const float*)d_in[12];
  const float* bt1 = (const float*)d_in[13];
  const float* Wt2 = (const float*)d_in[14];
  const float* bt2 = (const float*)d_in[15];
  const float* Wt3 = (const float*)d_in[16];
  const float* bt3 = (const float*)d_in[17];
  float* out = (float*)d_out;

  char* ws = (char*)d_ws;
  size_t off = 0;
  auto alloc = [&](size_t bytes) {
    char* p = ws + off;
    off += (bytes + 255) & ~(size_t)255;
    return p;
  };
  __hip_bfloat16* emb  = (__hip_bfloat16*)alloc((size_t)B_SZ * D_DIM * 2);
  __hip_bfloat16* We1T = (__hip_bfloat16*)alloc((size_t)E_EXP * BOT0 * D_DIM * 2);
  __hip_bfloat16* We2T = (__hip_bfloat16*)alloc((size_t)E_EXP * BOT1 * BOT0 * 2);
  __hip_bfloat16* H    = (__hip_bfloat16*)alloc((size_t)E_EXP * B_SZ * BOT0 * 2);
  __hip_bfloat16* fea  = (__hip_bfloat16*)alloc((size_t)E_EXP * B_SZ * BOT1 * 2);
  float* gate = (float*)alloc((size_t)T_TASK * B_SZ * E_EXP * 4);
  __hip_bfloat16* WgT  = (__hip_bfloat16*)alloc((size_t)T_TASK * E_EXP * D_DIM * 2);
  (void)alloc(4096); // slack: gemm tail prefetch reads overrun up to ~256 B

  hipFuncSetAttribute((const void*)gemm8p,
                      hipFuncAttributeMaxDynamicSharedMemorySize, 131072);
  hipFuncSetAttribute((const void*)gemm4p,
                      hipFuncAttributeMaxDynamicSharedMemorySize, 98304);

  // 1. fused weight prep (We1T, We2T, WgT)
  prep_weights<<<dim3(8044), 256, 0, stream>>>(We1, We2, Wg, We1T, We2T, WgT);

  // 2. embedding gather + numeric linear
  embed_convert<<<dim3(B_SZ / 4), 256, 0, stream>>>(cat, numx, offsets, W_emb, Wn, bnv, emb);

  // 3. gate GEMM + softmax
  gate_mfma<<<dim3(B_SZ / 64), 256, 0, stream>>>(emb, WgT, bg, gate);

  // 4. expert layer 1: (4096x1728)x(1728x512) x8 -> H   [256 blocks = 1/CU]
  gemm8p<<<dim3(B_SZ / 256, BOT0 / 256, E_EXP), 512, 131072, stream>>>(
      emb, (size_t)0, We1T, be1, H, B_SZ, BOT0, D_DIM);

  // 5. expert layer 2: (4096x512)x(512x256) x8 -> fea   [32x1x8 = 256 blocks]
  gemm4p<<<dim3(B_SZ / 128, BOT1 / 256, E_EXP), 512, 98304, stream>>>(
      H, (size_t)B_SZ * BOT0, We2T, be2, fea, B_SZ, BOT1, BOT0);

  // 6. gated combine + towers + sigmoid
  combine_tower<<<dim3(B_SZ / TB, T_TASK), 256, 0, stream>>>(
      gate, fea, Wt1, bt1, Wt2, bt2, Wt3, bt3, out);
}

// Round 7
// 130.288 us; speedup vs baseline: 2.6390x; 1.0090x over previous
//
#include <hip/hip_runtime.h>
#include <hip/hip_bf16.h>

#define B_SZ 4096
#define F_CAT 26
#define NUM_N 13
#define ED 64
#define D_DIM 1728   // 27*64
#define E_EXP 8
#define T_TASK 2
#define BOT0 512
#define BOT1 256
#define TOW0 128
#define TOW1 64

typedef __bf16 bf16x8 __attribute__((ext_vector_type(8)));
typedef float f32x4 __attribute__((ext_vector_type(4)));

__device__ __forceinline__ void gload_lds16(const void* g, void* l) {
  __builtin_amdgcn_global_load_lds(
      (const __attribute__((address_space(1))) void*)g,
      (__attribute__((address_space(3))) void*)l, 16, 0, 0);
}

#define BAR() do { asm volatile("" ::: "memory"); __builtin_amdgcn_s_barrier(); asm volatile("" ::: "memory"); } while (0)
#define VM6() asm volatile("s_waitcnt vmcnt(6)" ::: "memory")
#define VM4() asm volatile("s_waitcnt vmcnt(4)" ::: "memory")

// ---------------- f32 -> OCP e4m3fn (RNE, saturating) ----------------
__device__ __forceinline__ unsigned char f2e4m3(float x) {
  unsigned su = (__float_as_uint(x) >> 24) & 0x80u;
  float ax = fabsf(x);
  if (!(ax < 448.f)) return (unsigned char)(su | 0x7E);  // sat / NaN -> max
  if (ax == 0.f) return (unsigned char)su;
  int e;
  float m = frexpf(ax, &e);        // ax = m * 2^e, m in [0.5,1)
  int E = e - 1;                   // ax = (2m) * 2^E
  if (E < -6) {                    // subnormal: step 2^-9
    int mi = (int)rintf(ldexpf(ax, 9));
    if (mi >= 8) return (unsigned char)(su | 0x08);
    return (unsigned char)(su | mi);
  }
  int mi = (int)rintf(ldexpf(m, 4));  // [8,16]
  if (mi == 16) { mi = 8; E += 1; if (E > 8) return (unsigned char)(su | 0x7E); }
  return (unsigned char)(su | ((E + 7) << 3) | (mi - 8));
}

// ---------------- fused weight prep ----------------
// We1 (e,1728,512) f32 -> We1T8 (e,512,1728) fp8 e4m3, scaled x16
// We2 (e,512,256)  f32 -> We2T  (e,256,512)  bf16
// Wg  (T,D,E)      f32 -> WgT   (T*E, D)     bf16
__device__ __forceinline__ void trans_tile_bf16(
    const float* __restrict__ inp, __hip_bfloat16* __restrict__ outp,
    int R, int C, int cx, int ry, float (*tile)[33])
{
  int c0 = cx * 32, r0 = ry * 32;
  int tx = threadIdx.x & 31, ty = threadIdx.x >> 5; // 32 x 8
#pragma unroll
  for (int i = 0; i < 32; i += 8)
    tile[ty + i][tx] = inp[(size_t)(r0 + ty + i) * C + c0 + tx];
  __syncthreads();
#pragma unroll
  for (int i = 0; i < 32; i += 8)
    outp[(size_t)(c0 + ty + i) * R + r0 + tx] = __float2bfloat16(tile[tx][ty + i]);
}

__device__ __forceinline__ void trans_tile_fp8(
    const float* __restrict__ inp, unsigned char* __restrict__ outp,
    int R, int C, int cx, int ry, float (*tile)[33])
{
  int c0 = cx * 32, r0 = ry * 32;
  int tx = threadIdx.x & 31, ty = threadIdx.x >> 5;
#pragma unroll
  for (int i = 0; i < 32; i += 8)
    tile[ty + i][tx] = inp[(size_t)(r0 + ty + i) * C + c0 + tx];
  __syncthreads();
#pragma unroll
  for (int i = 0; i < 32; i += 8)
    outp[(size_t)(c0 + ty + i) * R + r0 + tx] = f2e4m3(tile[tx][ty + i] * 16.f);
}

// We1 tiles: 8x54x16 = 6912 ; We2 tiles: 8x16x8 = 1024 ; Wg: 108 blocks
__global__ __launch_bounds__(256) void prep_weights(
    const float* __restrict__ We1, const float* __restrict__ We2,
    const float* __restrict__ Wg,
    unsigned char* __restrict__ We1T8, __hip_bfloat16* __restrict__ We2T,
    __hip_bfloat16* __restrict__ WgT)
{
  __shared__ float tile[32][33];
  int id = blockIdx.x;
  if (id < 6912) {
    int z = id / 864, r = id - z * 864;
    int cx = r & 15, ry = r >> 4;
    trans_tile_fp8(We1 + (size_t)z * D_DIM * BOT0, We1T8 + (size_t)z * D_DIM * BOT0,
                   D_DIM, BOT0, cx, ry, tile);
  } else if (id < 7936) {
    int r2 = id - 6912;
    int z = r2 >> 7, r = r2 & 127;
    int cx = r & 7, ry = r >> 3;
    trans_tile_bf16(We2 + (size_t)z * BOT0 * BOT1, We2T + (size_t)z * BOT0 * BOT1,
                    BOT0, BOT1, cx, ry, tile);
  } else {
    int i = (id - 7936) * 256 + threadIdx.x; // over 16*1728
    int n = i / D_DIM, d = i - n * D_DIM;
    int t = n >> 3, e2 = n & 7;
    WgT[i] = __float2bfloat16(Wg[((size_t)t * D_DIM + d) * E_EXP + e2]);
  }
}

// ---------------- embedding gather + numeric linear -> emb bf16 + emb8 fp8(x16)
__global__ __launch_bounds__(256) void embed_convert(
    const int* __restrict__ cat, const float* __restrict__ numx,
    const int* __restrict__ offsets, const float* __restrict__ W_emb,
    const float* __restrict__ Wn, const float* __restrict__ bnum,
    __hip_bfloat16* __restrict__ emb, unsigned char* __restrict__ emb8)
{
  const int UNITS = 27 * 16; // float4 units per row
  int b0 = blockIdx.x * 4;
  for (int idx = threadIdx.x; idx < 4 * UNITS; idx += 256) {
    int r = idx / UNITS, u = idx - r * UNITS;
    int f = u >> 4, d4 = (u & 15) * 4;
    int b = b0 + r;
    float4 v;
    if (f < F_CAT) {
      int row = cat[(size_t)b * F_CAT + f] + offsets[f];
      v = *reinterpret_cast<const float4*>(&W_emb[(size_t)row * ED + d4]);
    } else {
      float a0 = bnum[d4], a1 = bnum[d4 + 1], a2 = bnum[d4 + 2], a3 = bnum[d4 + 3];
#pragma unroll
      for (int n = 0; n < NUM_N; ++n) {
        float x = numx[(size_t)b * NUM_N + n];
        const float* wr = &Wn[n * ED + d4];
        a0 = fmaf(x, wr[0], a0);
        a1 = fmaf(x, wr[1], a1);
        a2 = fmaf(x, wr[2], a2);
        a3 = fmaf(x, wr[3], a3);
      }
      v = make_float4(a0, a1, a2, a3);
    }
    union { __hip_bfloat16 h[4]; uint2 u2; } pk;
    pk.h[0] = __float2bfloat16(v.x);
    pk.h[1] = __float2bfloat16(v.y);
    pk.h[2] = __float2bfloat16(v.z);
    pk.h[3] = __float2bfloat16(v.w);
    size_t base = (size_t)b * D_DIM + f * ED + d4;
    *reinterpret_cast<uint2*>(&emb[base]) = pk.u2;
    union { unsigned char c[4]; unsigned int w; } p8;
    p8.c[0] = f2e4m3(v.x * 16.f);
    p8.c[1] = f2e4m3(v.y * 16.f);
    p8.c[2] = f2e4m3(v.z * 16.f);
    p8.c[3] = f2e4m3(v.w * 16.f);
    *reinterpret_cast<unsigned int*>(&emb8[base]) = p8.w;
  }
}

// ---------------- gate GEMM (M=4096, N=16, K=1728) via MFMA + fused softmax
__global__ __launch_bounds__(256) void gate_mfma(
    const __hip_bfloat16* __restrict__ emb, const __hip_bfloat16* __restrict__ WgT,
    const float* __restrict__ bg, float* __restrict__ gate)
{
  int wid = threadIdx.x >> 6, lane = threadIdx.x & 63;
  int l15 = lane & 15, lh = lane >> 4;
  int r0 = (blockIdx.x * 4 + wid) * 16;
  f32x4 acc = {};
  const __hip_bfloat16* arow = emb + (size_t)(r0 + l15) * D_DIM + lh * 8;
  const __hip_bfloat16* brow = WgT + (size_t)l15 * D_DIM + lh * 8;
#pragma unroll 4
  for (int k = 0; k < D_DIM; k += 32) {
    bf16x8 af = *reinterpret_cast<const bf16x8*>(arow + k);
    bf16x8 bf = *reinterpret_cast<const bf16x8*>(brow + k);
    acc = __builtin_amdgcn_mfma_f32_16x16x32_bf16(af, bf, acc, 0, 0, 0);
  }
  int t = l15 >> 3, e = l15 & 7;
  float bv = bg[t * E_EXP + e];
#pragma unroll
  for (int r = 0; r < 4; ++r) {
    float lg = acc[r] + bv;
    float m = lg;
    m = fmaxf(m, __shfl_xor(m, 1));
    m = fmaxf(m, __shfl_xor(m, 2));
    m = fmaxf(m, __shfl_xor(m, 4));
    float ex = expf(lg - m);
    float s = ex;
    s += __shfl_xor(s, 1);
    s += __shfl_xor(s, 2);
    s += __shfl_xor(s, 4);
    int row = r0 + lh * 4 + r;
    gate[((size_t)t * B_SZ + row) * E_EXP + e] = ex / s;
  }
}

__device__ __forceinline__ void mfma16(const bf16x8* a, const bf16x8* b, f32x4 (*accRows)[4]) {
#pragma unroll
  for (int i = 0; i < 4; ++i)
#pragma unroll
    for (int j = 0; j < 4; ++j)
      accRows[i][j] = __builtin_amdgcn_mfma_f32_16x16x32_bf16(a[i], b[j], accRows[i][j], 0, 0, 0);
}

__device__ __forceinline__ void mfma16f8(const long* a, const long* b, f32x4 (*accRows)[4]) {
#pragma unroll
  for (int i = 0; i < 4; ++i)
#pragma unroll
    for (int j = 0; j < 4; ++j)
      accRows[i][j] = __builtin_amdgcn_mfma_f32_16x16x32_fp8_fp8(a[i], b[j], accRows[i][j], 0, 0, 0);
}

// =========================================================================
// FP8 8-phase 256x256 BK=64 GEMM (GEMM1). Same verified schedule as the
// bf16 gemm8p, with e4m3 operands (both sides pre-scaled x16; epilogue
// applies 1/256). Halved LDS traffic: frag = 8 B/lane (ds_read_b64),
// half-slab = 256 rows x 32 B = 8 KB, 1 gload/thread/phase, VM4 cadence.
// fp8 swizzle: slot(8B) ^= ((row>>2)&1)<<1 — 16-B-granule-preserving
// involution; read pattern = 2 lanes/bank (free). Output bf16 H via
// LDS-staged coalesced epilogue (cs = 128 KB; loop uses 64 KB).
// =========================================================================
__global__ __launch_bounds__(512, 2) void gemm8p_fp8(
    const unsigned char* __restrict__ A8, size_t strideAe,
    const unsigned char* __restrict__ BT8,
    const float* __restrict__ bias,
    __hip_bfloat16* __restrict__ C,
    int M, int N, int K)
{
  extern __shared__ char smem[];
  int e = blockIdx.z;
  const unsigned char* Ap = A8 + strideAe * (size_t)e;
  const unsigned char* Bp = BT8 + (size_t)e * N * K;
  const float* bp = bias + (size_t)e * N;
  __hip_bfloat16* Cp = C + (size_t)e * M * N;
  int bm0 = blockIdx.x * 256, bn0 = blockIdx.y * 256;

  int tid = threadIdx.x;
  int wid = tid >> 6, lane = tid & 63;
  int l15 = lane & 15, lh = lane >> 4;
  int wrow = (wid >> 2) * 128, wcol = (wid & 3) * 64;

  // LDS read bases: slot = lh ^ ((l15>>2 & 1)<<1)  (8-B slots in 32-B rows)
  int slotc = (lh ^ (((l15 >> 2) & 1) << 1)) << 3;
  const char* rdA = smem + (wrow + l15) * 32 + slotc;
  const char* rdB = smem + 32768 + (wcol + l15) * 32 + slotc;
  char* stA = smem + (wid << 10);           // 8 waves x 1 KB = 8 KB half-slab
  char* stB = smem + 32768 + (wid << 10);

  // global staging: thread covers 16 B = granule g of row (tid>>1);
  // source granule pre-swizzled: g' = g ^ ((row>>2)&1)
  int srow = tid >> 1;
  int gsw = (tid & 1) ^ ((srow >> 2) & 1);
  const unsigned char* gA = Ap + (size_t)(bm0 + srow) * K + gsw * 16;
  const unsigned char* gB = Bp + (size_t)(bn0 + srow) * K + gsw * 16;

  f32x4 acc[8][4] = {};
  int NT = K >> 6;

  // prologue: T0k0, T0k1, T1k0 (6 loads/thread); VM4 certifies T0k0
  gload_lds16(gA, stA);           gload_lds16(gB, stB);
  gload_lds16(gA + 32, stA + 8192); gload_lds16(gB + 32, stB + 8192);
  gload_lds16(gA + 64, stA + 16384); gload_lds16(gB + 64, stB + 16384);
  VM4();
  BAR();

  for (int T = 0; T < NT; ++T) {
    int par = (T & 1) << 14;   // cur buffer byte offset (16 KB per buffer)
    int qar = par ^ 16384;
    const char* As = rdA + par;
    const char* Bs = rdB + par;
    long a[4], b[4];

    // p0: k0, rows wrow..+63; stage A-k1(T+1)
#pragma unroll
    for (int i = 0; i < 4; ++i) a[i] = *(const long*)(As + i * 512);
#pragma unroll
    for (int j = 0; j < 4; ++j) b[j] = *(const long*)(Bs + j * 512);
    gload_lds16(gA + 96, stA + qar + 8192);
    BAR();
    __builtin_amdgcn_s_setprio(1); mfma16f8(a, b, acc); __builtin_amdgcn_s_setprio(0);
    BAR();

    // p1: k0, rows +64..127; stage B-k1(T+1); VM4 certifies cur-k1
#pragma unroll
    for (int i = 0; i < 4; ++i) a[i] = *(const long*)(As + 2048 + i * 512);
    gload_lds16(gB + 96, stB + qar + 8192);
    BAR();
    __builtin_amdgcn_s_setprio(1); mfma16f8(a, b, acc + 4); __builtin_amdgcn_s_setprio(0);
    VM4();
    BAR();

    // p2: k1, rows wrow..+63; stage A-k0(T+2)
#pragma unroll
    for (int i = 0; i < 4; ++i) a[i] = *(const long*)(As + 8192 + i * 512);
#pragma unroll
    for (int j = 0; j < 4; ++j) b[j] = *(const long*)(Bs + 8192 + j * 512);
    gload_lds16(gA + 128, stA + par);
    BAR();
    __builtin_amdgcn_s_setprio(1); mfma16f8(a, b, acc); __builtin_amdgcn_s_setprio(0);
    BAR();

    // p3: k1, rows +64..127; stage B-k0(T+2); VM4 certifies next-k0
#pragma unroll
    for (int i = 0; i < 4; ++i) a[i] = *(const long*)(As + 8192 + 2048 + i * 512);
    gload_lds16(gB + 128, stB + par);
    BAR();
    __builtin_amdgcn_s_setprio(1); mfma16f8(a, b, acc + 4); __builtin_amdgcn_s_setprio(0);
    VM4();
    BAR();

    gA += 64; gB += 64;
  }

  // epilogue: drain tail prefetches, scale 1/256 + bias + relu -> bf16 cs,
  // then fully coalesced 16 B/lane stores.
  asm volatile("s_waitcnt vmcnt(0)" ::: "memory");
  BAR();
  __hip_bfloat16* cs = (__hip_bfloat16*)smem;
#pragma unroll
  for (int nj = 0; nj < 4; ++nj) {
    int col = wcol + nj * 16 + l15;
    float bv = bp[bn0 + col];
#pragma unroll
    for (int mi = 0; mi < 8; ++mi) {
      int rb = wrow + mi * 16 + lh * 4;
#pragma unroll
      for (int r = 0; r < 4; ++r) {
        float v = acc[mi][nj][r] * (1.f / 256.f) + bv;
        cs[(size_t)(rb + r) * 256 + col] = __float2bfloat16(fmaxf(v, 0.f));
      }
    }
  }
  BAR();
  {
    int rr = tid >> 5, c8 = (tid & 31) * 8;
#pragma unroll
    for (int p = 0; p < 16; ++p) {
      int row = p * 16 + rr;
      *reinterpret_cast<uint4*>(&Cp[(size_t)(bm0 + row) * N + bn0 + c8]) =
          *reinterpret_cast<const uint4*>(&cs[(size_t)row * 256 + c8]);
    }
  }
}

// =========================================================================
// bf16 BM=128 variant (gemm4p) for GEMM2 — unchanged (proven).
// =========================================================================
__global__ __launch_bounds__(512, 2) void gemm4p(
    const __hip_bfloat16* __restrict__ A, size_t strideAe,
    const __hip_bfloat16* __restrict__ BT,
    const float* __restrict__ bias,
    __hip_bfloat16* __restrict__ C,
    int M, int N, int K)
{
  extern __shared__ char smem[];
  int e = blockIdx.z;
  const __hip_bfloat16* Ap = A + strideAe * (size_t)e;
  const __hip_bfloat16* Bp = BT + (size_t)e * N * K;
  const float* bp = bias + (size_t)e * N;
  __hip_bfloat16* Cp = C + (size_t)e * M * N;
  int bm0 = blockIdx.x * 128, bn0 = blockIdx.y * 256;

  int tid = threadIdx.x;
  int wid = tid >> 6, lane = tid & 63;
  int l15 = lane & 15, lh = lane >> 4;
  int wrow = (wid >> 2) * 64, wcol = (wid & 3) * 64;

  int slotc = (lh ^ (((l15 >> 3) & 1) << 1)) << 4;
  const char* rdA = smem + (wrow + l15) * 64 + slotc;
  const char* rdB = smem + 32768 + (wcol + l15) * 64 + slotc;
  char* stA = smem + (wid << 10);
  char* stB = smem + 32768 + (wid << 10);

  const __hip_bfloat16* gA;
  const __hip_bfloat16* gB[2];
  {
    int X = (wid << 10) + (lane << 4);
    int row = X >> 6;
    int ss = ((X >> 4) & 3) ^ (((row >> 3) & 1) << 1);
    gA = Ap + (size_t)(bm0 + row) * K + ss * 8;
#pragma unroll
    for (int j = 0; j < 2; ++j) {
      int X2 = X + (j << 13);
      int row2 = X2 >> 6;
      int ss2 = ((X2 >> 4) & 3) ^ (((row2 >> 3) & 1) << 1);
      gB[j] = Bp + (size_t)(bn0 + row2) * K + ss2 * 8;
    }
  }

  f32x4 acc[4][4] = {};
  int NT = K >> 6;

  gload_lds16(gA, stA);
#pragma unroll
  for (int j = 0; j < 2; ++j) gload_lds16(gB[j], stB + (j << 13));
  gload_lds16(gA + 32, stA + 8192);
#pragma unroll
  for (int j = 0; j < 2; ++j) gload_lds16(gB[j] + 32, stB + 16384 + (j << 13));
  gload_lds16(gA + 64, stA + 16384);
#pragma unroll
  for (int j = 0; j < 2; ++j) gload_lds16(gB[j] + 64, stB + 32768 + (j << 13));
  VM6();
  BAR();

  for (int T = 0; T < NT; ++T) {
    int pA = (T & 1) << 14, qA = pA ^ 16384;
    int pB = (T & 1) << 15, qB = pB ^ 32768;
    const char* As = rdA + pA;
    const char* Bs = rdB + pB;
    bf16x8 a[4], b[4];

#pragma unroll
    for (int i = 0; i < 4; ++i) a[i] = *(const bf16x8*)(As + i * 1024);
#pragma unroll
    for (int j = 0; j < 4; ++j) b[j] = *(const bf16x8*)(Bs + j * 1024);
    gload_lds16(gA + 96, stA + qA + 8192);
#pragma unroll
    for (int j = 0; j < 2; ++j) gload_lds16(gB[j] + 96, stB + qB + 16384 + (j << 13));
    BAR();
    __builtin_amdgcn_s_setprio(1); mfma16(a, b, acc); __builtin_amdgcn_s_setprio(0);
    VM6();
    BAR();

#pragma unroll
    for (int i = 0; i < 4; ++i) a[i] = *(const bf16x8*)(As + 8192 + i * 1024);
#pragma unroll
    for (int j = 0; j < 4; ++j) b[j] = *(const bf16x8*)(Bs + 16384 + j * 1024);
    gload_lds16(gA + 128, stA + pA);
#pragma unroll
    for (int j = 0; j < 2; ++j) gload_lds16(gB[j] + 128, stB + pB + (j << 13));
    BAR();
    __builtin_amdgcn_s_setprio(1); mfma16(a, b, acc); __builtin_amdgcn_s_setprio(0);
    VM6();
    BAR();

    gA += 64;
#pragma unroll
    for (int j = 0; j < 2; ++j) gB[j] += 64;
  }

  asm volatile("s_waitcnt vmcnt(0)" ::: "memory");
  BAR();
  __hip_bfloat16* cs = (__hip_bfloat16*)smem;
#pragma unroll
  for (int nj = 0; nj < 4; ++nj) {
    int col = wcol + nj * 16 + l15;
    float bv = bp[bn0 + col];
#pragma unroll
    for (int mi = 0; mi < 4; ++mi) {
      int rb = wrow + mi * 16 + lh * 4;
#pragma unroll
      for (int r = 0; r < 4; ++r) {
        float v = acc[mi][nj][r] + bv;
        cs[(size_t)(rb + r) * 256 + col] = __float2bfloat16(fmaxf(v, 0.f));
      }
    }
  }
  BAR();
  {
    int rr = tid >> 5, c8 = (tid & 31) * 8;
#pragma unroll
    for (int p = 0; p < 8; ++p) {
      int row = p * 16 + rr;
      *reinterpret_cast<uint4*>(&Cp[(size_t)(bm0 + row) * N + bn0 + c8]) =
          *reinterpret_cast<const uint4*>(&cs[(size_t)row * 256 + c8]);
    }
  }
}

// ---------------- gate-combine + tower MLPs + sigmoid (16 batch rows per block)
#define TB 16
__global__ __launch_bounds__(256) void combine_tower(
    const float* __restrict__ gate, const __hip_bfloat16* __restrict__ fea,
    const float* __restrict__ Wt1, const float* __restrict__ bt1,
    const float* __restrict__ Wt2, const float* __restrict__ bt2,
    const float* __restrict__ Wt3, const float* __restrict__ bt3,
    float* __restrict__ out)
{
  int t = blockIdx.y;
  int b0 = blockIdx.x * TB;
  int tid = threadIdx.x;
  __shared__ float gs[TB][E_EXP];
  __shared__ float tf[TB][BOT1];
  __shared__ float h1[TB][TOW0];
  __shared__ float h2[TB][TOW1];
  if (tid < TB * E_EXP) {
    int bl = tid >> 3, e = tid & 7;
    gs[bl][e] = gate[((size_t)t * B_SZ + b0 + bl) * E_EXP + e];
  }
  __syncthreads();
  for (int i = tid; i < TB * BOT1; i += 256) {
    int bl = i >> 8, o = i & 255;
    float s = 0.f;
#pragma unroll
    for (int e = 0; e < E_EXP; ++e)
      s = fmaf(gs[bl][e], __bfloat162float(fea[((size_t)e * B_SZ + b0 + bl) * BOT1 + o]), s);
    tf[bl][o] = s;
  }
  __syncthreads();
  {
    int h = tid & 127, half = tid >> 7;
    float a[8] = {0, 0, 0, 0, 0, 0, 0, 0};
    for (int d = 0; d < BOT1; ++d) {
      float w = Wt1[((size_t)t * BOT1 + d) * TOW0 + h];
#pragma unroll
      for (int q = 0; q < 8; ++q) a[q] = fmaf(w, tf[half * 8 + q][d], a[q]);
    }
    float bv = bt1[t * TOW0 + h];
#pragma unroll
    for (int q = 0; q < 8; ++q) h1[half * 8 + q][h] = fmaxf(a[q] + bv, 0.f);
  }
  __syncthreads();
  {
    int h = tid & 63, qt = tid >> 6;
    float a[4] = {0, 0, 0, 0};
    for (int d = 0; d < TOW0; ++d) {
      float w = Wt2[((size_t)t * TOW0 + d) * TOW1 + h];
#pragma unroll
      for (int q = 0; q < 4; ++q) a[q] = fmaf(w, h1[qt * 4 + q][d], a[q]);
    }
    float bv = bt2[t * TOW1 + h];
#pragma unroll
    for (int q = 0; q < 4; ++q) h2[qt * 4 + q][h] = fmaxf(a[q] + bv, 0.f);
  }
  __syncthreads();
  {
    int l16 = tid & 15, bl = tid >> 4;
    float p = 0.f;
#pragma unroll
    for (int d = l16; d < TOW1; d += 16) p = fmaf(h2[bl][d], Wt3[t * TOW1 + d], p);
#pragma unroll
    for (int o = 8; o; o >>= 1) p += __shfl_down(p, o, 16);
    if (l16 == 0) {
      float lg = p + bt3[t];
      out[(size_t)t * B_SZ + b0 + bl] = 1.f / (1.f + expf(-lg));
    }
  }
}

extern "C" void kernel_launch(void* const* d_in, const int* in_sizes, int n_in,
                              void* d_out, int out_size, void* d_ws, size_t ws_size,
                              hipStream_t stream) {
  const int* cat = (const int*)d_in[0];
  const float* numx = (const float*)d_in[1];
  const int* offsets = (const int*)d_in[2];
  const float* W_emb = (const float*)d_in[3];
  const float* Wn = (const float*)d_in[4];
  const float* bnv = (const float*)d_in[5];
  const float* We1 = (const float*)d_in[6];
  const float* be1 = (const float*)d_in[7];
  const float* We2 = (const float*)d_in[8];
  const float* be2 = (const float*)d_in[9];
  const float* Wg = (const float*)d_in[10];
  const float* bg = (const float*)d_in[11];
  const float* Wt1 = (const float*)d_in[12];
  const float* bt1 = (const float*)d_in[13];
  const float* Wt2 = (const float*)d_in[14];
  const float* bt2 = (const float*)d_in[15];
  const float* Wt3 = (const float*)d_in[16];
  const float* bt3 = (const float*)d_in[17];
  float* out = (float*)d_out;

  char* ws = (char*)d_ws;
  size_t off = 0;
  auto alloc = [&](size_t bytes) {
    char* p = ws + off;
    off += (bytes + 255) & ~(size_t)255;
    return p;
  };
  __hip_bfloat16* emb   = (__hip_bfloat16*)alloc((size_t)B_SZ * D_DIM * 2);
  unsigned char*  emb8  = (unsigned char*)alloc((size_t)B_SZ * D_DIM);
  unsigned char*  We1T8 = (unsigned char*)alloc((size_t)E_EXP * BOT0 * D_DIM);
  __hip_bfloat16* We2T  = (__hip_bfloat16*)alloc((size_t)E_EXP * BOT1 * BOT0 * 2);
  __hip_bfloat16* H     = (__hip_bfloat16*)alloc((size_t)E_EXP * B_SZ * BOT0 * 2);
  __hip_bfloat16* fea   = (__hip_bfloat16*)alloc((size_t)E_EXP * B_SZ * BOT1 * 2);
  float* gate = (float*)alloc((size_t)T_TASK * B_SZ * E_EXP * 4);
  __hip_bfloat16* WgT   = (__hip_bfloat16*)alloc((size_t)T_TASK * E_EXP * D_DIM * 2);
  (void)alloc(4096); // slack: gemm tail prefetch reads overrun up to ~256 B

  hipFuncSetAttribute((const void*)gemm8p_fp8,
                      hipFuncAttributeMaxDynamicSharedMemorySize, 131072);
  hipFuncSetAttribute((const void*)gemm4p,
                      hipFuncAttributeMaxDynamicSharedMemorySize, 98304);

  // 1. fused weight prep (We1T8 fp8 x16, We2T bf16, WgT bf16)
  prep_weights<<<dim3(8044), 256, 0, stream>>>(We1, We2, Wg, We1T8, We2T, WgT);

  // 2. embedding gather + numeric linear (bf16 emb for gate, fp8 x16 emb8 for GEMM1)
  embed_convert<<<dim3(B_SZ / 4), 256, 0, stream>>>(cat, numx, offsets, W_emb, Wn, bnv, emb, emb8);

  // 3. gate GEMM + softmax
  gate_mfma<<<dim3(B_SZ / 64), 256, 0, stream>>>(emb, WgT, bg, gate);

  // 4. expert layer 1 (fp8): (4096x1728)x(1728x512) x8 -> H bf16  [256 blocks]
  gemm8p_fp8<<<dim3(B_SZ / 256, BOT0 / 256, E_EXP), 512, 131072, stream>>>(
      emb8, (size_t)0, We1T8, be1, H, B_SZ, BOT0, D_DIM);

  // 5. expert layer 2 (bf16): (4096x512)x(512x256) x8 -> fea  [256 blocks]
  gemm4p<<<dim3(B_SZ / 128, BOT1 / 256, E_EXP), 512, 98304, stream>>>(
      H, (size_t)B_SZ * BOT0, We2T, be2, fea, B_SZ, BOT1, BOT0);

  // 6. gated combine + towers + sigmoid
  combine_tower<<<dim3(B_SZ / TB, T_TASK), 256, 0, stream>>>(
      gate, fea, Wt1, bt1, Wt2, bt2, Wt3, bt3, out);
}

// Round 8
// 128.652 us; speedup vs baseline: 2.6726x; 1.0127x over previous
//
#include <hip/hip_runtime.h>
#include <hip/hip_bf16.h>

#define B_SZ 4096
#define F_CAT 26
#define NUM_N 13
#define ED 64
#define D_DIM 1728   // 27*64
#define E_EXP 8
#define T_TASK 2
#define BOT0 512
#define BOT1 256
#define TOW0 128
#define TOW1 64

typedef __bf16 bf16x8 __attribute__((ext_vector_type(8)));
typedef float f32x4 __attribute__((ext_vector_type(4)));
typedef long lx2 __attribute__((ext_vector_type(2)));

__device__ __forceinline__ void gload_lds16(const void* g, void* l) {
  __builtin_amdgcn_global_load_lds(
      (const __attribute__((address_space(1))) void*)g,
      (__attribute__((address_space(3))) void*)l, 16, 0, 0);
}

#define BAR() do { asm volatile("" ::: "memory"); __builtin_amdgcn_s_barrier(); asm volatile("" ::: "memory"); } while (0)
#define VM6() asm volatile("s_waitcnt vmcnt(6)" ::: "memory")
#define VM4() asm volatile("s_waitcnt vmcnt(4)" ::: "memory")

// fp8 k-permutation within each 64-k block: LDS/global position p <-> k so that
// one 16-B read at slot lh yields both K=32 fragments for lane (l15,lh):
// p = (k&7) + ((k>>3)&3)*16 + ((k>>5)&1)*8
__device__ __forceinline__ int permk(int k6) {
  return (k6 & 7) + (((k6 >> 3) & 3) << 4) + (((k6 >> 5) & 1) << 3);
}

// ---------------- f32 -> OCP e4m3fn (RNE, saturating) ----------------
__device__ __forceinline__ unsigned char f2e4m3(float x) {
  unsigned su = (__float_as_uint(x) >> 24) & 0x80u;
  float ax = fabsf(x);
  if (!(ax < 448.f)) return (unsigned char)(su | 0x7E);  // sat / NaN -> max
  if (ax == 0.f) return (unsigned char)su;
  int e;
  float m = frexpf(ax, &e);        // ax = m * 2^e, m in [0.5,1)
  int E = e - 1;                   // ax = (2m) * 2^E
  if (E < -6) {                    // subnormal: step 2^-9
    int mi = (int)rintf(ldexpf(ax, 9));
    if (mi >= 8) return (unsigned char)(su | 0x08);
    return (unsigned char)(su | mi);
  }
  int mi = (int)rintf(ldexpf(m, 4));  // [8,16]
  if (mi == 16) { mi = 8; E += 1; if (E > 8) return (unsigned char)(su | 0x7E); }
  return (unsigned char)(su | ((E + 7) << 3) | (mi - 8));
}

// ---------------- fused weight prep ----------------
__device__ __forceinline__ void trans_tile_bf16(
    const float* __restrict__ inp, __hip_bfloat16* __restrict__ outp,
    int R, int C, int cx, int ry, float (*tile)[33])
{
  int c0 = cx * 32, r0 = ry * 32;
  int tx = threadIdx.x & 31, ty = threadIdx.x >> 5; // 32 x 8
#pragma unroll
  for (int i = 0; i < 32; i += 8)
    tile[ty + i][tx] = inp[(size_t)(r0 + ty + i) * C + c0 + tx];
  __syncthreads();
#pragma unroll
  for (int i = 0; i < 32; i += 8)
    outp[(size_t)(c0 + ty + i) * R + r0 + tx] = __float2bfloat16(tile[tx][ty + i]);
}

__device__ __forceinline__ void trans_tile_fp8(
    const float* __restrict__ inp, unsigned char* __restrict__ outp,
    int R, int C, int cx, int ry, float (*tile)[33])
{
  int c0 = cx * 32, r0 = ry * 32;
  int tx = threadIdx.x & 31, ty = threadIdx.x >> 5;
#pragma unroll
  for (int i = 0; i < 32; i += 8)
    tile[ty + i][tx] = inp[(size_t)(r0 + ty + i) * C + c0 + tx];
  __syncthreads();
  int ki = r0 + tx;
  int outk = (ki & ~63) + permk(ki & 63);
#pragma unroll
  for (int i = 0; i < 32; i += 8)
    outp[(size_t)(c0 + ty + i) * R + outk] = f2e4m3(tile[tx][ty + i] * 16.f);
}

// We1 tiles: 6912 ; We2 tiles: 1024 ; Wg: 108 blocks
__global__ __launch_bounds__(256) void prep_weights(
    const float* __restrict__ We1, const float* __restrict__ We2,
    const float* __restrict__ Wg,
    unsigned char* __restrict__ We1T8, __hip_bfloat16* __restrict__ We2T,
    __hip_bfloat16* __restrict__ WgT)
{
  __shared__ float tile[32][33];
  int id = blockIdx.x;
  if (id < 6912) {
    int z = id / 864, r = id - z * 864;
    int cx = r & 15, ry = r >> 4;
    trans_tile_fp8(We1 + (size_t)z * D_DIM * BOT0, We1T8 + (size_t)z * D_DIM * BOT0,
                   D_DIM, BOT0, cx, ry, tile);
  } else if (id < 7936) {
    int r2 = id - 6912;
    int z = r2 >> 7, r = r2 & 127;
    int cx = r & 7, ry = r >> 3;
    trans_tile_bf16(We2 + (size_t)z * BOT0 * BOT1, We2T + (size_t)z * BOT0 * BOT1,
                    BOT0, BOT1, cx, ry, tile);
  } else {
    int i = (id - 7936) * 256 + threadIdx.x; // over 16*1728
    int n = i / D_DIM, d = i - n * D_DIM;
    int t = n >> 3, e2 = n & 7;
    WgT[i] = __float2bfloat16(Wg[((size_t)t * D_DIM + d) * E_EXP + e2]);
  }
}

// ---------------- embedding gather + numeric linear -> emb bf16 + emb8 fp8(x16, k-permuted)
__global__ __launch_bounds__(256) void embed_convert(
    const int* __restrict__ cat, const float* __restrict__ numx,
    const int* __restrict__ offsets, const float* __restrict__ W_emb,
    const float* __restrict__ Wn, const float* __restrict__ bnum,
    __hip_bfloat16* __restrict__ emb, unsigned char* __restrict__ emb8)
{
  const int UNITS = 27 * 16; // float4 units per row
  int b0 = blockIdx.x * 4;
  for (int idx = threadIdx.x; idx < 4 * UNITS; idx += 256) {
    int r = idx / UNITS, u = idx - r * UNITS;
    int f = u >> 4, d4 = (u & 15) * 4;
    int b = b0 + r;
    float4 v;
    if (f < F_CAT) {
      int row = cat[(size_t)b * F_CAT + f] + offsets[f];
      v = *reinterpret_cast<const float4*>(&W_emb[(size_t)row * ED + d4]);
    } else {
      float a0 = bnum[d4], a1 = bnum[d4 + 1], a2 = bnum[d4 + 2], a3 = bnum[d4 + 3];
#pragma unroll
      for (int n = 0; n < NUM_N; ++n) {
        float x = numx[(size_t)b * NUM_N + n];
        const float* wr = &Wn[n * ED + d4];
        a0 = fmaf(x, wr[0], a0);
        a1 = fmaf(x, wr[1], a1);
        a2 = fmaf(x, wr[2], a2);
        a3 = fmaf(x, wr[3], a3);
      }
      v = make_float4(a0, a1, a2, a3);
    }
    union { __hip_bfloat16 h[4]; uint2 u2; } pk;
    pk.h[0] = __float2bfloat16(v.x);
    pk.h[1] = __float2bfloat16(v.y);
    pk.h[2] = __float2bfloat16(v.z);
    pk.h[3] = __float2bfloat16(v.w);
    *reinterpret_cast<uint2*>(&emb[(size_t)b * D_DIM + f * ED + d4]) = pk.u2;
    union { unsigned char c[4]; unsigned int w; } p8;
    p8.c[0] = f2e4m3(v.x * 16.f);
    p8.c[1] = f2e4m3(v.y * 16.f);
    p8.c[2] = f2e4m3(v.z * 16.f);
    p8.c[3] = f2e4m3(v.w * 16.f);
    int pb = (d4 & 7) + (((d4 >> 3) & 3) << 4) + (((d4 >> 5) & 1) << 3);
    *reinterpret_cast<unsigned int*>(&emb8[(size_t)b * D_DIM + f * ED + pb]) = p8.w;
  }
}

// ---------------- gate GEMM (M=4096, N=16, K=1728) via MFMA + fused softmax
__global__ __launch_bounds__(256) void gate_mfma(
    const __hip_bfloat16* __restrict__ emb, const __hip_bfloat16* __restrict__ WgT,
    const float* __restrict__ bg, float* __restrict__ gate)
{
  int wid = threadIdx.x >> 6, lane = threadIdx.x & 63;
  int l15 = lane & 15, lh = lane >> 4;
  int r0 = (blockIdx.x * 4 + wid) * 16;
  f32x4 acc = {};
  const __hip_bfloat16* arow = emb + (size_t)(r0 + l15) * D_DIM + lh * 8;
  const __hip_bfloat16* brow = WgT + (size_t)l15 * D_DIM + lh * 8;
#pragma unroll 4
  for (int k = 0; k < D_DIM; k += 32) {
    bf16x8 af = *reinterpret_cast<const bf16x8*>(arow + k);
    bf16x8 bf = *reinterpret_cast<const bf16x8*>(brow + k);
    acc = __builtin_amdgcn_mfma_f32_16x16x32_bf16(af, bf, acc, 0, 0, 0);
  }
  int t = l15 >> 3, e = l15 & 7;
  float bv = bg[t * E_EXP + e];
#pragma unroll
  for (int r = 0; r < 4; ++r) {
    float lg = acc[r] + bv;
    float m = lg;
    m = fmaxf(m, __shfl_xor(m, 1));
    m = fmaxf(m, __shfl_xor(m, 2));
    m = fmaxf(m, __shfl_xor(m, 4));
    float ex = expf(lg - m);
    float s = ex;
    s += __shfl_xor(s, 1);
    s += __shfl_xor(s, 2);
    s += __shfl_xor(s, 4);
    int row = r0 + lh * 4 + r;
    gate[((size_t)t * B_SZ + row) * E_EXP + e] = ex / s;
  }
}

__device__ __forceinline__ void mfma16(const bf16x8* a, const bf16x8* b, f32x4 (*accRows)[4]) {
#pragma unroll
  for (int i = 0; i < 4; ++i)
#pragma unroll
    for (int j = 0; j < 4; ++j)
      accRows[i][j] = __builtin_amdgcn_mfma_f32_16x16x32_bf16(a[i], b[j], accRows[i][j], 0, 0, 0);
}

// =========================================================================
// FP8 2-phase 256x256 BK=64 GEMM (GEMM1). LDS geometry IDENTICAL to the
// proven bf16 pattern: 64-B rows, 16-B slots, slot ^= ((row>>3)&1)<<1,
// ds_read_b128 — one read delivers BOTH K=32 fragments via the k-perm
// global layout (permk). Triple-buffered 16-KB A/B slabs (96 KB loop,
// 128 KB epilogue). Per tile: 4 gloads at p0 into buf (T+2)%3; one VM4
// at p1-end certifies (T+1) (3 phases old). 32-MFMA clusters, 4 BAR/tile.
// Operands pre-scaled x16 both sides; epilogue applies 1/256.
// =========================================================================
__global__ __launch_bounds__(512, 2) void gemm8p_fp8(
    const unsigned char* __restrict__ A8, size_t strideAe,
    const unsigned char* __restrict__ BT8,
    const float* __restrict__ bias,
    __hip_bfloat16* __restrict__ C,
    int M, int N, int K)
{
  extern __shared__ char smem[];
  int e = blockIdx.z;
  const unsigned char* Ap = A8 + strideAe * (size_t)e;
  const unsigned char* Bp = BT8 + (size_t)e * N * K;
  const float* bp = bias + (size_t)e * N;
  __hip_bfloat16* Cp = C + (size_t)e * M * N;
  int bm0 = blockIdx.x * 256, bn0 = blockIdx.y * 256;

  int tid = threadIdx.x;
  int wid = tid >> 6, lane = tid & 63;
  int l15 = lane & 15, lh = lane >> 4;
  int wrow = (wid >> 2) * 128, wcol = (wid & 3) * 64;

  // LDS read bases (proven bf16 swizzle; row bit3 == l15 bit3)
  int slotc = (lh ^ (((l15 >> 3) & 1) << 1)) << 4;
  const char* rdA = smem + (wrow + l15) * 64 + slotc;
  const char* rdB = smem + 49152 + (wcol + l15) * 64 + slotc;
  char* stA = smem + (wid << 10);
  char* stB = smem + 49152 + (wid << 10);

  // global staging: thread covers LDS bytes tid*16 of a 16-KB slab
  int srow = tid >> 2;                                   // 0..127
  int ssw = (tid & 3) ^ (((srow >> 3) & 1) << 1);        // pre-swizzled source slot
  const unsigned char* gA0 = Ap + (size_t)(bm0 + srow) * K + ssw * 16;
  const unsigned char* gA1 = Ap + (size_t)(bm0 + 128 + srow) * K + ssw * 16;
  const unsigned char* gB0 = Bp + (size_t)(bn0 + srow) * K + ssw * 16;
  const unsigned char* gB1 = Bp + (size_t)(bn0 + 128 + srow) * K + ssw * 16;

  auto STAGE = [&](int koff, int buf) {
    gload_lds16(gA0 + koff, stA + buf * 16384);
    gload_lds16(gA1 + koff, stA + buf * 16384 + 8192);
    gload_lds16(gB0 + koff, stB + buf * 16384);
    gload_lds16(gB1 + koff, stB + buf * 16384 + 8192);
  };

  f32x4 acc[8][4] = {};
  int NT = K >> 6;

  // prologue: T0 -> buf0, T1 -> buf1; VM4 certifies T0
  STAGE(0, 0);
  STAGE(64, 1);
  VM4();
  BAR();

  int bufc = 0, koff = 128;
  for (int T = 0; T < NT; ++T) {
    const char* As = rdA + bufc * 16384;
    const char* Bs = rdB + bufc * 16384;
    int sb = bufc >= 1 ? bufc - 1 : 2;   // (bufc+2)%3
    lx2 va[4], vb[4];

    // ---- p0: rows wrow..+63, both K-halves; stage tile T+2
#pragma unroll
    for (int i = 0; i < 4; ++i) va[i] = *(const lx2*)(As + i * 1024);
#pragma unroll
    for (int j = 0; j < 4; ++j) vb[j] = *(const lx2*)(Bs + j * 1024);
    STAGE(koff, sb);
    BAR();
    __builtin_amdgcn_s_setprio(1);
#pragma unroll
    for (int i = 0; i < 4; ++i)
#pragma unroll
      for (int j = 0; j < 4; ++j)
        acc[i][j] = __builtin_amdgcn_mfma_f32_16x16x32_fp8_fp8(va[i][0], vb[j][0], acc[i][j], 0, 0, 0);
#pragma unroll
    for (int i = 0; i < 4; ++i)
#pragma unroll
      for (int j = 0; j < 4; ++j)
        acc[i][j] = __builtin_amdgcn_mfma_f32_16x16x32_fp8_fp8(va[i][1], vb[j][1], acc[i][j], 0, 0, 0);
    __builtin_amdgcn_s_setprio(0);
    BAR();

    // ---- p1: rows wrow+64..+127 (B frags reused); VM4 certifies T+1
#pragma unroll
    for (int i = 0; i < 4; ++i) va[i] = *(const lx2*)(As + 4096 + i * 1024);
    BAR();
    __builtin_amdgcn_s_setprio(1);
#pragma unroll
    for (int i = 0; i < 4; ++i)
#pragma unroll
      for (int j = 0; j < 4; ++j)
        acc[4 + i][j] = __builtin_amdgcn_mfma_f32_16x16x32_fp8_fp8(va[i][0], vb[j][0], acc[4 + i][j], 0, 0, 0);
#pragma unroll
    for (int i = 0; i < 4; ++i)
#pragma unroll
      for (int j = 0; j < 4; ++j)
        acc[4 + i][j] = __builtin_amdgcn_mfma_f32_16x16x32_fp8_fp8(va[i][1], vb[j][1], acc[4 + i][j], 0, 0, 0);
    __builtin_amdgcn_s_setprio(0);
    VM4();
    BAR();

    koff += 64;
    bufc = bufc == 2 ? 0 : bufc + 1;
  }

  // epilogue: drain tail prefetches (they land in LDS!), scale 1/256 + bias
  // + relu -> bf16 cs, then fully coalesced 16 B/lane stores.
  asm volatile("s_waitcnt vmcnt(0)" ::: "memory");
  BAR();
  __hip_bfloat16* cs = (__hip_bfloat16*)smem;
#pragma unroll
  for (int nj = 0; nj < 4; ++nj) {
    int col = wcol + nj * 16 + l15;
    float bv = bp[bn0 + col];
#pragma unroll
    for (int mi = 0; mi < 8; ++mi) {
      int rb = wrow + mi * 16 + lh * 4;
#pragma unroll
      for (int r = 0; r < 4; ++r) {
        float v = acc[mi][nj][r] * (1.f / 256.f) + bv;
        cs[(size_t)(rb + r) * 256 + col] = __float2bfloat16(fmaxf(v, 0.f));
      }
    }
  }
  BAR();
  {
    int rr = tid >> 5, c8 = (tid & 31) * 8;
#pragma unroll
    for (int p = 0; p < 16; ++p) {
      int row = p * 16 + rr;
      *reinterpret_cast<uint4*>(&Cp[(size_t)(bm0 + row) * N + bn0 + c8]) =
          *reinterpret_cast<const uint4*>(&cs[(size_t)row * 256 + c8]);
    }
  }
}

// =========================================================================
// bf16 BM=128 variant (gemm4p) for GEMM2 — unchanged (proven).
// =========================================================================
__global__ __launch_bounds__(512, 2) void gemm4p(
    const __hip_bfloat16* __restrict__ A, size_t strideAe,
    const __hip_bfloat16* __restrict__ BT,
    const float* __restrict__ bias,
    __hip_bfloat16* __restrict__ C,
    int M, int N, int K)
{
  extern __shared__ char smem[];
  int e = blockIdx.z;
  const __hip_bfloat16* Ap = A + strideAe * (size_t)e;
  const __hip_bfloat16* Bp = BT + (size_t)e * N * K;
  const float* bp = bias + (size_t)e * N;
  __hip_bfloat16* Cp = C + (size_t)e * M * N;
  int bm0 = blockIdx.x * 128, bn0 = blockIdx.y * 256;

  int tid = threadIdx.x;
  int wid = tid >> 6, lane = tid & 63;
  int l15 = lane & 15, lh = lane >> 4;
  int wrow = (wid >> 2) * 64, wcol = (wid & 3) * 64;

  int slotc = (lh ^ (((l15 >> 3) & 1) << 1)) << 4;
  const char* rdA = smem + (wrow + l15) * 64 + slotc;
  const char* rdB = smem + 32768 + (wcol + l15) * 64 + slotc;
  char* stA = smem + (wid << 10);
  char* stB = smem + 32768 + (wid << 10);

  const __hip_bfloat16* gA;
  const __hip_bfloat16* gB[2];
  {
    int X = (wid << 10) + (lane << 4);
    int row = X >> 6;
    int ss = ((X >> 4) & 3) ^ (((row >> 3) & 1) << 1);
    gA = Ap + (size_t)(bm0 + row) * K + ss * 8;
#pragma unroll
    for (int j = 0; j < 2; ++j) {
      int X2 = X + (j << 13);
      int row2 = X2 >> 6;
      int ss2 = ((X2 >> 4) & 3) ^ (((row2 >> 3) & 1) << 1);
      gB[j] = Bp + (size_t)(bn0 + row2) * K + ss2 * 8;
    }
  }

  f32x4 acc[4][4] = {};
  int NT = K >> 6;

  gload_lds16(gA, stA);
#pragma unroll
  for (int j = 0; j < 2; ++j) gload_lds16(gB[j], stB + (j << 13));
  gload_lds16(gA + 32, stA + 8192);
#pragma unroll
  for (int j = 0; j < 2; ++j) gload_lds16(gB[j] + 32, stB + 16384 + (j << 13));
  gload_lds16(gA + 64, stA + 16384);
#pragma unroll
  for (int j = 0; j < 2; ++j) gload_lds16(gB[j] + 64, stB + 32768 + (j << 13));
  VM6();
  BAR();

  for (int T = 0; T < NT; ++T) {
    int pA = (T & 1) << 14, qA = pA ^ 16384;
    int pB = (T & 1) << 15, qB = pB ^ 32768;
    const char* As = rdA + pA;
    const char* Bs = rdB + pB;
    bf16x8 a[4], b[4];

#pragma unroll
    for (int i = 0; i < 4; ++i) a[i] = *(const bf16x8*)(As + i * 1024);
#pragma unroll
    for (int j = 0; j < 4; ++j) b[j] = *(const bf16x8*)(Bs + j * 1024);
    gload_lds16(gA + 96, stA + qA + 8192);
#pragma unroll
    for (int j = 0; j < 2; ++j) gload_lds16(gB[j] + 96, stB + qB + 16384 + (j << 13));
    BAR();
    __builtin_amdgcn_s_setprio(1); mfma16(a, b, acc); __builtin_amdgcn_s_setprio(0);
    VM6();
    BAR();

#pragma unroll
    for (int i = 0; i < 4; ++i) a[i] = *(const bf16x8*)(As + 8192 + i * 1024);
#pragma unroll
    for (int j = 0; j < 4; ++j) b[j] = *(const bf16x8*)(Bs + 16384 + j * 1024);
    gload_lds16(gA + 128, stA + pA);
#pragma unroll
    for (int j = 0; j < 2; ++j) gload_lds16(gB[j] + 128, stB + pB + (j << 13));
    BAR();
    __builtin_amdgcn_s_setprio(1); mfma16(a, b, acc); __builtin_amdgcn_s_setprio(0);
    VM6();
    BAR();

    gA += 64;
#pragma unroll
    for (int j = 0; j < 2; ++j) gB[j] += 64;
  }

  asm volatile("s_waitcnt vmcnt(0)" ::: "memory");
  BAR();
  __hip_bfloat16* cs = (__hip_bfloat16*)smem;
#pragma unroll
  for (int nj = 0; nj < 4; ++nj) {
    int col = wcol + nj * 16 + l15;
    float bv = bp[bn0 + col];
#pragma unroll
    for (int mi = 0; mi < 4; ++mi) {
      int rb = wrow + mi * 16 + lh * 4;
#pragma unroll
      for (int r = 0; r < 4; ++r) {
        float v = acc[mi][nj][r] + bv;
        cs[(size_t)(rb + r) * 256 + col] = __float2bfloat16(fmaxf(v, 0.f));
      }
    }
  }
  BAR();
  {
    int rr = tid >> 5, c8 = (tid & 31) * 8;
#pragma unroll
    for (int p = 0; p < 8; ++p) {
      int row = p * 16 + rr;
      *reinterpret_cast<uint4*>(&Cp[(size_t)(bm0 + row) * N + bn0 + c8]) =
          *reinterpret_cast<const uint4*>(&cs[(size_t)row * 256 + c8]);
    }
  }
}

// ---------------- gate-combine + tower MLPs + sigmoid (16 batch rows per block)
#define TB 16
__global__ __launch_bounds__(256) void combine_tower(
    const float* __restrict__ gate, const __hip_bfloat16* __restrict__ fea,
    const float* __restrict__ Wt1, const float* __restrict__ bt1,
    const float* __restrict__ Wt2, const float* __restrict__ bt2,
    const float* __restrict__ Wt3, const float* __restrict__ bt3,
    float* __restrict__ out)
{
  int t = blockIdx.y;
  int b0 = blockIdx.x * TB;
  int tid = threadIdx.x;
  __shared__ float gs[TB][E_EXP];
  __shared__ float tf[TB][BOT1];
  __shared__ float h1[TB][TOW0];
  __shared__ float h2[TB][TOW1];
  if (tid < TB * E_EXP) {
    int bl = tid >> 3, e = tid & 7;
    gs[bl][e] = gate[((size_t)t * B_SZ + b0 + bl) * E_EXP + e];
  }
  __syncthreads();
  for (int i = tid; i < TB * BOT1; i += 256) {
    int bl = i >> 8, o = i & 255;
    float s = 0.f;
#pragma unroll
    for (int e = 0; e < E_EXP; ++e)
      s = fmaf(gs[bl][e], __bfloat162float(fea[((size_t)e * B_SZ + b0 + bl) * BOT1 + o]), s);
    tf[bl][o] = s;
  }
  __syncthreads();
  {
    int h = tid & 127, half = tid >> 7;
    float a[8] = {0, 0, 0, 0, 0, 0, 0, 0};
    for (int d = 0; d < BOT1; ++d) {
      float w = Wt1[((size_t)t * BOT1 + d) * TOW0 + h];
#pragma unroll
      for (int q = 0; q < 8; ++q) a[q] = fmaf(w, tf[half * 8 + q][d], a[q]);
    }
    float bv = bt1[t * TOW0 + h];
#pragma unroll
    for (int q = 0; q < 8; ++q) h1[half * 8 + q][h] = fmaxf(a[q] + bv, 0.f);
  }
  __syncthreads();
  {
    int h = tid & 63, qt = tid >> 6;
    float a[4] = {0, 0, 0, 0};
    for (int d = 0; d < TOW0; ++d) {
      float w = Wt2[((size_t)t * TOW0 + d) * TOW1 + h];
#pragma unroll
      for (int q = 0; q < 4; ++q) a[q] = fmaf(w, h1[qt * 4 + q][d], a[q]);
    }
    float bv = bt2[t * TOW1 + h];
#pragma unroll
    for (int q = 0; q < 4; ++q) h2[qt * 4 + q][h] = fmaxf(a[q] + bv, 0.f);
  }
  __syncthreads();
  {
    int l16 = tid & 15, bl = tid >> 4;
    float p = 0.f;
#pragma unroll
    for (int d = l16; d < TOW1; d += 16) p = fmaf(h2[bl][d], Wt3[t * TOW1 + d], p);
#pragma unroll
    for (int o = 8; o; o >>= 1) p += __shfl_down(p, o, 16);
    if (l16 == 0) {
      float lg = p + bt3[t];
      out[(size_t)t * B_SZ + b0 + bl] = 1.f / (1.f + expf(-lg));
    }
  }
}

extern "C" void kernel_launch(void* const* d_in, const int* in_sizes, int n_in,
                              void* d_out, int out_size, void* d_ws, size_t ws_size,
                              hipStream_t stream) {
  const int* cat = (const int*)d_in[0];
  const float* numx = (const float*)d_in[1];
  const int* offsets = (const int*)d_in[2];
  const float* W_emb = (const float*)d_in[3];
  const float* Wn = (const float*)d_in[4];
  const float* bnv = (const float*)d_in[5];
  const float* We1 = (const float*)d_in[6];
  const float* be1 = (const float*)d_in[7];
  const float* We2 = (const float*)d_in[8];
  const float* be2 = (const float*)d_in[9];
  const float* Wg = (const float*)d_in[10];
  const float* bg = (const float*)d_in[11];
  const float* Wt1 = (const float*)d_in[12];
  const float* bt1 = (const float*)d_in[13];
  const float* Wt2 = (const float*)d_in[14];
  const float* bt2 = (const float*)d_in[15];
  const float* Wt3 = (const float*)d_in[16];
  const float* bt3 = (const float*)d_in[17];
  float* out = (float*)d_out;

  char* ws = (char*)d_ws;
  size_t off = 0;
  auto alloc = [&](size_t bytes) {
    char* p = ws + off;
    off += (bytes + 255) & ~(size_t)255;
    return p;
  };
  __hip_bfloat16* emb   = (__hip_bfloat16*)alloc((size_t)B_SZ * D_DIM * 2);
  unsigned char*  emb8  = (unsigned char*)alloc((size_t)B_SZ * D_DIM);
  unsigned char*  We1T8 = (unsigned char*)alloc((size_t)E_EXP * BOT0 * D_DIM);
  __hip_bfloat16* We2T  = (__hip_bfloat16*)alloc((size_t)E_EXP * BOT1 * BOT0 * 2);
  __hip_bfloat16* H     = (__hip_bfloat16*)alloc((size_t)E_EXP * B_SZ * BOT0 * 2);
  __hip_bfloat16* fea   = (__hip_bfloat16*)alloc((size_t)E_EXP * B_SZ * BOT1 * 2);
  float* gate = (float*)alloc((size_t)T_TASK * B_SZ * E_EXP * 4);
  __hip_bfloat16* WgT   = (__hip_bfloat16*)alloc((size_t)T_TASK * E_EXP * D_DIM * 2);
  (void)alloc(4096); // slack: gemm tail prefetch reads overrun up to ~256 B

  hipFuncSetAttribute((const void*)gemm8p_fp8,
                      hipFuncAttributeMaxDynamicSharedMemorySize, 131072);
  hipFuncSetAttribute((const void*)gemm4p,
                      hipFuncAttributeMaxDynamicSharedMemorySize, 98304);

  // 1. fused weight prep (We1T8 fp8 x16 k-permuted, We2T bf16, WgT bf16)
  prep_weights<<<dim3(8044), 256, 0, stream>>>(We1, We2, Wg, We1T8, We2T, WgT);

  // 2. embedding gather + numeric linear (bf16 emb for gate, fp8 x16 k-permuted emb8)
  embed_convert<<<dim3(B_SZ / 4), 256, 0, stream>>>(cat, numx, offsets, W_emb, Wn, bnv, emb, emb8);

  // 3. gate GEMM + softmax
  gate_mfma<<<dim3(B_SZ / 64), 256, 0, stream>>>(emb, WgT, bg, gate);

  // 4. expert layer 1 (fp8): (4096x1728)x(1728x512) x8 -> H bf16  [256 blocks]
  gemm8p_fp8<<<dim3(B_SZ / 256, BOT0 / 256, E_EXP), 512, 131072, stream>>>(
      emb8, (size_t)0, We1T8, be1, H, B_SZ, BOT0, D_DIM);

  // 5. expert layer 2 (bf16): (4096x512)x(512x256) x8 -> fea  [256 blocks]
  gemm4p<<<dim3(B_SZ / 128, BOT1 / 256, E_EXP), 512, 98304, stream>>>(
      H, (size_t)B_SZ * BOT0, We2T, be2, fea, B_SZ, BOT1, BOT0);

  // 6. gated combine + towers + sigmoid
  combine_tower<<<dim3(B_SZ / TB, T_TASK), 256, 0, stream>>>(
      gate, fea, Wt1, bt1, Wt2, bt2, Wt3, bt3, out);
}